// Round 1
// baseline (2502.035 us; speedup 1.0000x reference)
//
#include <hip/hip_runtime.h>
#include <hip/hip_bf16.h>
#include <math.h>

#define N_TOK 32768
#define DIMX 512
#define HEADS 8
#define DHEAD 64
#define ANUM 256
#define QKV_COLS 1536
#define SCALE_Q 0.125f
#define KVCHUNK 1024
#define NCHUNK 32

// ---------------- K1: qkv[m, j] = sum_k x[m,k] * W[j,k] ----------------
__global__ __launch_bounds__(256) void k_qkv(const float* __restrict__ x,
                                             const float* __restrict__ W,
                                             float* __restrict__ qkv) {
    __shared__ __align__(16) float As[16][68];  // [k][m], padded row 68 (272B, 16B-mult)
    __shared__ __align__(16) float Bs[16][68];  // [k][j]
    const int tid = threadIdx.x;
    const int m0 = blockIdx.y * 64;
    const int j0 = blockIdx.x * 64;
    const int tm = (tid >> 4) * 4;
    const int tj = (tid & 15) * 4;
    const int lr = tid >> 2;
    const int lc = (tid & 3) * 4;
    float c[4][4] = {};
    const float* xp = x + (size_t)(m0 + lr) * DIMX + lc;
    const float* wp = W + (size_t)(j0 + lr) * DIMX + lc;
    for (int k0 = 0; k0 < DIMX; k0 += 16) {
        float4 av = *(const float4*)(xp + k0);
        float4 bv = *(const float4*)(wp + k0);
        __syncthreads();
        As[lc+0][lr] = av.x; As[lc+1][lr] = av.y; As[lc+2][lr] = av.z; As[lc+3][lr] = av.w;
        Bs[lc+0][lr] = bv.x; Bs[lc+1][lr] = bv.y; Bs[lc+2][lr] = bv.z; Bs[lc+3][lr] = bv.w;
        __syncthreads();
        #pragma unroll
        for (int kk = 0; kk < 16; ++kk) {
            float4 a = *(const float4*)&As[kk][tm];
            float4 b = *(const float4*)&Bs[kk][tj];
            c[0][0] += a.x*b.x; c[0][1] += a.x*b.y; c[0][2] += a.x*b.z; c[0][3] += a.x*b.w;
            c[1][0] += a.y*b.x; c[1][1] += a.y*b.y; c[1][2] += a.y*b.z; c[1][3] += a.y*b.w;
            c[2][0] += a.z*b.x; c[2][1] += a.z*b.y; c[2][2] += a.z*b.z; c[2][3] += a.z*b.w;
            c[3][0] += a.w*b.x; c[3][1] += a.w*b.y; c[3][2] += a.w*b.z; c[3][3] += a.w*b.w;
        }
    }
    #pragma unroll
    for (int i = 0; i < 4; ++i) {
        *(float4*)&qkv[(size_t)(m0+tm+i)*QKV_COLS + j0 + tj] =
            make_float4(c[i][0], c[i][1], c[i][2], c[i][3]);
    }
}

// ---------------- K2: per (h, n-chunk) partial of softmax(agent.k over n) @ v ----------------
// fixed exp shift 20: logits |l| <= ~64 so exp(l-20) fits fp32 over 32768-sums; partials add exactly.
__global__ __launch_bounds__(256) void k_kvagg(const float* __restrict__ qkv,
                                               const float* __restrict__ agent,
                                               float* __restrict__ pacc,
                                               float* __restrict__ psum) {
    __shared__ __align__(16) float kt[64][64];
    __shared__ __align__(16) float vt[64][64];
    const int h = blockIdx.x;
    const int chunk = blockIdx.y;
    const int t = threadIdx.x;       // = agent index a (0..255)
    float ar[64];
    #pragma unroll
    for (int d4 = 0; d4 < 16; ++d4) {
        float4 v = *(const float4*)&agent[((size_t)h*ANUM + t)*DHEAD + d4*4];
        ar[d4*4+0]=v.x; ar[d4*4+1]=v.y; ar[d4*4+2]=v.z; ar[d4*4+3]=v.w;
    }
    float acc[64] = {};
    float s = 0.f;
    const int row = t >> 2;
    const int c0 = (t & 3) * 16;
    const int n0 = chunk * KVCHUNK;
    for (int nt = 0; nt < KVCHUNK; nt += 64) {
        const float* kb = qkv + (size_t)(n0+nt+row)*QKV_COLS + DIMX + h*DHEAD + c0;
        const float* vb = kb + DIMX;
        __syncthreads();
        #pragma unroll
        for (int i = 0; i < 4; ++i) {
            *(float4*)&kt[row][c0 + i*4] = *(const float4*)(kb + i*4);
            *(float4*)&vt[row][c0 + i*4] = *(const float4*)(vb + i*4);
        }
        __syncthreads();
        for (int n = 0; n < 64; ++n) {
            float l = 0.f;
            #pragma unroll
            for (int d4 = 0; d4 < 16; ++d4) {
                float4 k4 = *(const float4*)&kt[n][d4*4];
                l += ar[d4*4+0]*k4.x + ar[d4*4+1]*k4.y + ar[d4*4+2]*k4.z + ar[d4*4+3]*k4.w;
            }
            float p = __expf(l - 20.f);
            s += p;
            #pragma unroll
            for (int d4 = 0; d4 < 16; ++d4) {
                float4 v4 = *(const float4*)&vt[n][d4*4];
                acc[d4*4+0] += p*v4.x; acc[d4*4+1] += p*v4.y;
                acc[d4*4+2] += p*v4.z; acc[d4*4+3] += p*v4.w;
            }
        }
    }
    float* pa = pacc + ((size_t)chunk*HEADS + h)*(ANUM*DHEAD) + (size_t)t*DHEAD;
    #pragma unroll
    for (int d4 = 0; d4 < 16; ++d4) {
        *(float4*)&pa[d4*4] = make_float4(acc[d4*4], acc[d4*4+1], acc[d4*4+2], acc[d4*4+3]);
    }
    psum[((size_t)chunk*HEADS + h)*ANUM + t] = s;
}

// ---------------- K2b: combine chunk partials -> kv[h,a,d] ----------------
__global__ __launch_bounds__(256) void k_combine(const float* __restrict__ pacc,
                                                 const float* __restrict__ psum,
                                                 float* __restrict__ kv) {
    const int idx = blockIdx.x * 256 + threadIdx.x;   // < 131072
    const int ha = idx >> 6;
    float a = 0.f, s = 0.f;
    for (int c = 0; c < NCHUNK; ++c) {
        a += pacc[(size_t)c*131072 + idx];
        s += psum[c*2048 + ha];
    }
    kv[idx] = a / s;
}

// ---------------- K3: thresh = sigmoid(mean(kv_c @ Wt^T + bt)) ----------------
__global__ __launch_bounds__(256) void k_thresh(const float* __restrict__ kv,
                                                const float* __restrict__ Wt,
                                                const float* __restrict__ bt,
                                                float* __restrict__ th) {
    __shared__ float red[256];
    const int t = threadIdx.x;
    float s = 0.f;
    for (int i = t; i < HEADS*ANUM*DHEAD; i += 256)
        s += kv[i] * Wt[i & (DIMX-1)];
    red[t] = s;
    __syncthreads();
    for (int off = 128; off > 0; off >>= 1) {
        if (t < off) red[t] += red[t + off];
        __syncthreads();
    }
    if (t == 0) {
        float m = red[0] / (float)ANUM + bt[0];
        th[0] = 1.f / (1.f + expf(-m));
    }
}

// ---------------- K4: gating + row softmax over d ----------------
__global__ __launch_bounds__(64) void k_gate(const float* __restrict__ kv,
                                             const float* __restrict__ Wn,
                                             const float* __restrict__ bn,
                                             const float* __restrict__ Wm,
                                             const float* __restrict__ bm,
                                             const float* __restrict__ th,
                                             float* __restrict__ kvf) {
    const int rowi = blockIdx.x;     // h*256+a, 0..2047
    const int d = threadIdx.x;       // 0..63
    __shared__ __align__(16) float r[64];
    r[d] = kv[(size_t)rowi*64 + d];
    __syncthreads();
    float sn = bn[d], sm = bm[d];
    #pragma unroll
    for (int j4 = 0; j4 < 16; ++j4) {
        float4 rr = *(const float4*)&r[j4*4];
        float4 w1 = *(const float4*)&Wn[d*64 + j4*4];
        float4 w2 = *(const float4*)&Wm[d*64 + j4*4];
        sn += rr.x*w1.x + rr.y*w1.y + rr.z*w1.z + rr.w*w1.w;
        sm += rr.x*w2.x + rr.y*w2.y + rr.z*w2.z + rr.w*w2.w;
    }
    float noise = 1.f/(1.f + __expf(-sn));
    float maskv = 1.f/(1.f + __expf(-sm));
    float tval = th[0];
    float val = r[d] * (maskv > tval ? 1.f : 0.f) + noise;
    float m = val;
    #pragma unroll
    for (int off = 32; off > 0; off >>= 1) m = fmaxf(m, __shfl_xor(m, off, 64));
    float e = __expf(val - m);
    float ssum = e;
    #pragma unroll
    for (int off = 32; off > 0; off >>= 1) ssum += __shfl_xor(ssum, off, 64);
    kvf[(size_t)rowi*64 + d] = e / ssum;
}

// ---------------- K5: out[n, h*64+d] = softmax_a(q.agent * s) @ kvf ----------------
__global__ __launch_bounds__(256) void k_out(const float* __restrict__ qkv,
                                             const float* __restrict__ agent,
                                             const float* __restrict__ kvf,
                                             float* __restrict__ out) {
    __shared__ __align__(16) float ag[64][64];
    __shared__ __align__(16) float kf[64][64];
    const int h = blockIdx.y;
    const int t = threadIdx.x;
    const int n = blockIdx.x * 256 + t;
    float qr[64];
    #pragma unroll
    for (int d4 = 0; d4 < 16; ++d4) {
        float4 v = *(const float4*)&qkv[(size_t)n*QKV_COLS + h*DHEAD + d4*4];
        qr[d4*4+0]=v.x; qr[d4*4+1]=v.y; qr[d4*4+2]=v.z; qr[d4*4+3]=v.w;
    }
    float acc[64] = {};
    float s = 0.f;
    const int row = t >> 2;
    const int c0 = (t & 3) * 16;
    for (int a0 = 0; a0 < ANUM; a0 += 64) {
        const float* ab = agent + ((size_t)h*ANUM + a0 + row)*DHEAD + c0;
        const float* kb = kvf + ((size_t)h*ANUM + a0 + row)*DHEAD + c0;
        __syncthreads();
        #pragma unroll
        for (int i = 0; i < 4; ++i) {
            *(float4*)&ag[row][c0 + i*4] = *(const float4*)(ab + i*4);
            *(float4*)&kf[row][c0 + i*4] = *(const float4*)(kb + i*4);
        }
        __syncthreads();
        for (int a = 0; a < 64; ++a) {
            float l = 0.f;
            #pragma unroll
            for (int d4 = 0; d4 < 16; ++d4) {
                float4 a4 = *(const float4*)&ag[a][d4*4];
                l += qr[d4*4+0]*a4.x + qr[d4*4+1]*a4.y + qr[d4*4+2]*a4.z + qr[d4*4+3]*a4.w;
            }
            float p = __expf(l * SCALE_Q);
            s += p;
            #pragma unroll
            for (int d4 = 0; d4 < 16; ++d4) {
                float4 k4 = *(const float4*)&kf[a][d4*4];
                acc[d4*4+0] += p*k4.x; acc[d4*4+1] += p*k4.y;
                acc[d4*4+2] += p*k4.z; acc[d4*4+3] += p*k4.w;
            }
        }
    }
    const float inv = 1.f / s;
    #pragma unroll
    for (int d4 = 0; d4 < 16; ++d4) {
        *(float4*)&out[(size_t)n*DIMX + h*DHEAD + d4*4] =
            make_float4(acc[d4*4]*inv, acc[d4*4+1]*inv, acc[d4*4+2]*inv, acc[d4*4+3]*inv);
    }
}

extern "C" void kernel_launch(void* const* d_in, const int* in_sizes, int n_in,
                              void* d_out, int out_size, void* d_ws, size_t ws_size,
                              hipStream_t stream) {
    const float* x     = (const float*)d_in[0];
    const float* Wqkv  = (const float*)d_in[1];
    const float* agent = (const float*)d_in[2];
    const float* Wn    = (const float*)d_in[3];
    const float* bn    = (const float*)d_in[4];
    const float* Wm    = (const float*)d_in[5];
    const float* bm    = (const float*)d_in[6];
    const float* Wt    = (const float*)d_in[7];
    const float* bt    = (const float*)d_in[8];
    float* out = (float*)d_out;

    // workspace layout (floats)
    const size_t QKV_F  = (size_t)N_TOK * QKV_COLS;         // 50331648
    const size_t PACC_F = (size_t)NCHUNK * HEADS * ANUM * DHEAD; // 4194304
    const size_t PSUM_F = (size_t)NCHUNK * HEADS * ANUM;    // 65536
    const size_t KV_F   = (size_t)HEADS * ANUM * DHEAD;     // 131072
    const size_t need = (QKV_F + PACC_F + PSUM_F + 2*KV_F + 16) * sizeof(float);
    if (ws_size < need) return;  // fail loudly via validation rather than corrupt

    float* ws   = (float*)d_ws;
    float* qkv  = ws;
    float* pacc = qkv + QKV_F;
    float* psum = pacc + PACC_F;
    float* kv   = psum + PSUM_F;
    float* kvf  = kv + KV_F;
    float* th   = kvf + KV_F;

    k_qkv   <<<dim3(QKV_COLS/64, N_TOK/64), 256, 0, stream>>>(x, Wqkv, qkv);
    k_kvagg <<<dim3(HEADS, NCHUNK),         256, 0, stream>>>(qkv, agent, pacc, psum);
    k_combine<<<512,                        256, 0, stream>>>(pacc, psum, kv);
    k_thresh<<<1,                           256, 0, stream>>>(kv, Wt, bt, th);
    k_gate  <<<HEADS*ANUM,                  64,  0, stream>>>(kv, Wn, bn, Wm, bm, th, kvf);
    k_out   <<<dim3(N_TOK/256, HEADS),      256, 0, stream>>>(qkv, agent, kvf, out);
}

// Round 3
// 1631.361 us; speedup vs baseline: 1.5337x; 1.5337x over previous
//
#include <hip/hip_runtime.h>
#include <hip/hip_bf16.h>
#include <math.h>

#define N_TOK 32768
#define DIMX 512
#define HEADS 8
#define DHEAD 64
#define ANUM 256
#define QKV_COLS 1536
#define SCALE_Q 0.125f
#define KVCHUNK 1024
#define NCHUNK 32

// ---------------- K1: qkv[m, j] = sum_k x[m,k] * W[j,k] ----------------
// 128x128 block tile, 8x8 micro-tile. A: [k][m] plain; B: [k][j] col-swizzled.
// Swizzle j -> j + (j>>5)*4 has max index 139 -> row width 144 (576B, 16B-aligned).
__global__ __launch_bounds__(256, 4) void k_qkv(const float* __restrict__ x,
                                                const float* __restrict__ W,
                                                float* __restrict__ qkv) {
    __shared__ __align__(16) float As[16][132];
    __shared__ __align__(16) float Bs[16][144];
    const int tid = threadIdx.x;
    const int m0 = blockIdx.y * 128;
    const int j0 = blockIdx.x * 128;
    const int tm = (tid >> 4) * 8;          // 0..120
    const int tj = (tid & 15) * 8;          // 0..120
    const int tjs = tj + ((tj >> 5) << 2);  // swizzled col, max 132
    const int lr = tid >> 1;                // 0..127
    const int lc = (tid & 1) * 8;           // 0 or 8
    const int jswz = lr + ((lr >> 5) << 2); // swizzled col for B writes, max 139
    float c[8][8] = {};
    const float* xp = x + (size_t)(m0 + lr) * DIMX + lc;
    const float* wp = W + (size_t)(j0 + lr) * DIMX + lc;
    for (int k0 = 0; k0 < DIMX; k0 += 16) {
        float4 a0 = *(const float4*)(xp + k0);
        float4 a1 = *(const float4*)(xp + k0 + 4);
        float4 b0 = *(const float4*)(wp + k0);
        float4 b1 = *(const float4*)(wp + k0 + 4);
        __syncthreads();
        As[lc+0][lr]=a0.x; As[lc+1][lr]=a0.y; As[lc+2][lr]=a0.z; As[lc+3][lr]=a0.w;
        As[lc+4][lr]=a1.x; As[lc+5][lr]=a1.y; As[lc+6][lr]=a1.z; As[lc+7][lr]=a1.w;
        Bs[lc+0][jswz]=b0.x; Bs[lc+1][jswz]=b0.y; Bs[lc+2][jswz]=b0.z; Bs[lc+3][jswz]=b0.w;
        Bs[lc+4][jswz]=b1.x; Bs[lc+5][jswz]=b1.y; Bs[lc+6][jswz]=b1.z; Bs[lc+7][jswz]=b1.w;
        __syncthreads();
        #pragma unroll
        for (int kk = 0; kk < 16; ++kk) {
            float4 aA = *(const float4*)&As[kk][tm];
            float4 aB = *(const float4*)&As[kk][tm+4];
            float4 bA = *(const float4*)&Bs[kk][tjs];
            float4 bB = *(const float4*)&Bs[kk][tjs+4];
            float am[8] = {aA.x,aA.y,aA.z,aA.w,aB.x,aB.y,aB.z,aB.w};
            float bn[8] = {bA.x,bA.y,bA.z,bA.w,bB.x,bB.y,bB.z,bB.w};
            #pragma unroll
            for (int i = 0; i < 8; ++i)
                #pragma unroll
                for (int j = 0; j < 8; ++j)
                    c[i][j] = fmaf(am[i], bn[j], c[i][j]);
        }
    }
    #pragma unroll
    for (int i = 0; i < 8; ++i) {
        float* op = &qkv[(size_t)(m0+tm+i)*QKV_COLS + j0 + tj];
        *(float4*)op     = make_float4(c[i][0], c[i][1], c[i][2], c[i][3]);
        *(float4*)(op+4) = make_float4(c[i][4], c[i][5], c[i][6], c[i][7]);
    }
}

// ---------------- K2: per (h, n-chunk) partial of softmax(agent.k over n) @ v ----------------
// Two-phase: phase1 logits->exp into LDS P; phase2 P@v into per-thread acc[16].
// fixed exp shift 20: logits |l| <= ~64 so exp(l-20) fits fp32; partials add exactly.
__global__ __launch_bounds__(1024, 4) void k_kvagg(const float* __restrict__ qkv,
                                                   const float* __restrict__ agent,
                                                   float* __restrict__ pacc,
                                                   float* __restrict__ psum) {
    __shared__ __align__(16) float kt[64][68];
    __shared__ __align__(16) float vt[64][68];
    __shared__ float P[64][256];
    const int h = blockIdx.x;
    const int chunk = blockIdx.y;
    const int t = threadIdx.x;
    const int a = t & 255;
    const int g = t >> 8;          // 0..3
    const int d0 = g * 16;
    float ar[64];
    #pragma unroll
    for (int d4 = 0; d4 < 16; ++d4) {
        float4 v = *(const float4*)&agent[((size_t)h*ANUM + a)*DHEAD + d4*4];
        ar[d4*4+0]=v.x; ar[d4*4+1]=v.y; ar[d4*4+2]=v.z; ar[d4*4+3]=v.w;
    }
    float acc[16] = {};
    float s = 0.f;
    const int lrow = t >> 4;        // 0..63
    const int lcol = (t & 15) * 4;  // 0..60
    const int n0 = chunk * KVCHUNK;
    for (int nt = 0; nt < KVCHUNK; nt += 64) {
        const float* kb = qkv + (size_t)(n0+nt+lrow)*QKV_COLS + DIMX + h*DHEAD + lcol;
        float4 k4g = *(const float4*)kb;
        float4 v4g = *(const float4*)(kb + DIMX);
        __syncthreads();
        *(float4*)&kt[lrow][lcol] = k4g;
        *(float4*)&vt[lrow][lcol] = v4g;
        __syncthreads();
        // phase 1: thread (a, g) computes logits for n in [g*16, g*16+16)
        #pragma unroll
        for (int nn = 0; nn < 16; ++nn) {
            const int n = d0 + nn;
            float l = 0.f;
            #pragma unroll
            for (int d4 = 0; d4 < 16; ++d4) {
                float4 k4 = *(const float4*)&kt[n][d4*4];
                l = fmaf(ar[d4*4+0], k4.x, l);
                l = fmaf(ar[d4*4+1], k4.y, l);
                l = fmaf(ar[d4*4+2], k4.z, l);
                l = fmaf(ar[d4*4+3], k4.w, l);
            }
            P[n][a] = __expf(l - 20.f);
        }
        __syncthreads();
        // phase 2: thread (a, g) accumulates d-slice [g*16, g*16+16)
        for (int n = 0; n < 64; ++n) {
            float p = P[n][a];
            s += p;
            #pragma unroll
            for (int d4 = 0; d4 < 4; ++d4) {
                float4 v4 = *(const float4*)&vt[n][d0 + d4*4];
                acc[d4*4+0] = fmaf(p, v4.x, acc[d4*4+0]);
                acc[d4*4+1] = fmaf(p, v4.y, acc[d4*4+1]);
                acc[d4*4+2] = fmaf(p, v4.z, acc[d4*4+2]);
                acc[d4*4+3] = fmaf(p, v4.w, acc[d4*4+3]);
            }
        }
    }
    float* pa = pacc + ((size_t)chunk*HEADS + h)*(ANUM*DHEAD) + (size_t)a*DHEAD + d0;
    #pragma unroll
    for (int d4 = 0; d4 < 4; ++d4)
        *(float4*)&pa[d4*4] = make_float4(acc[d4*4], acc[d4*4+1], acc[d4*4+2], acc[d4*4+3]);
    if (g == 0) psum[((size_t)chunk*HEADS + h)*ANUM + a] = s;
}

// ---------------- K2b: combine chunk partials -> kv[h,a,d] ----------------
__global__ __launch_bounds__(256) void k_combine(const float* __restrict__ pacc,
                                                 const float* __restrict__ psum,
                                                 float* __restrict__ kv) {
    const int idx = blockIdx.x * 256 + threadIdx.x;   // < 131072
    const int ha = idx >> 6;
    float a = 0.f, s = 0.f;
    for (int c = 0; c < NCHUNK; ++c) {
        a += pacc[(size_t)c*131072 + idx];
        s += psum[c*2048 + ha];
    }
    kv[idx] = a / s;
}

// ---------------- K3: thresh = sigmoid(mean(kv_c @ Wt^T + bt)) ----------------
__global__ __launch_bounds__(256) void k_thresh(const float* __restrict__ kv,
                                                const float* __restrict__ Wt,
                                                const float* __restrict__ bt,
                                                float* __restrict__ th) {
    __shared__ float red[256];
    const int t = threadIdx.x;
    float s = 0.f;
    for (int i = t; i < HEADS*ANUM*DHEAD; i += 256)
        s += kv[i] * Wt[i & (DIMX-1)];
    red[t] = s;
    __syncthreads();
    for (int off = 128; off > 0; off >>= 1) {
        if (t < off) red[t] += red[t + off];
        __syncthreads();
    }
    if (t == 0) {
        float m = red[0] / (float)ANUM + bt[0];
        th[0] = 1.f / (1.f + expf(-m));
    }
}

// ---------------- K4: gating + row softmax over d ----------------
__global__ __launch_bounds__(64) void k_gate(const float* __restrict__ kv,
                                             const float* __restrict__ Wn,
                                             const float* __restrict__ bn,
                                             const float* __restrict__ Wm,
                                             const float* __restrict__ bm,
                                             const float* __restrict__ th,
                                             float* __restrict__ kvf) {
    const int rowi = blockIdx.x;     // h*256+a, 0..2047
    const int d = threadIdx.x;       // 0..63
    __shared__ __align__(16) float r[64];
    r[d] = kv[(size_t)rowi*64 + d];
    __syncthreads();
    float sn = bn[d], sm = bm[d];
    #pragma unroll
    for (int j4 = 0; j4 < 16; ++j4) {
        float4 rr = *(const float4*)&r[j4*4];
        float4 w1 = *(const float4*)&Wn[d*64 + j4*4];
        float4 w2 = *(const float4*)&Wm[d*64 + j4*4];
        sn += rr.x*w1.x + rr.y*w1.y + rr.z*w1.z + rr.w*w1.w;
        sm += rr.x*w2.x + rr.y*w2.y + rr.z*w2.z + rr.w*w2.w;
    }
    float noise = 1.f/(1.f + __expf(-sn));
    float maskv = 1.f/(1.f + __expf(-sm));
    float tval = th[0];
    float val = r[d] * (maskv > tval ? 1.f : 0.f) + noise;
    float m = val;
    #pragma unroll
    for (int off = 32; off > 0; off >>= 1) m = fmaxf(m, __shfl_xor(m, off, 64));
    float e = __expf(val - m);
    float ssum = e;
    #pragma unroll
    for (int off = 32; off > 0; off >>= 1) ssum += __shfl_xor(ssum, off, 64);
    kvf[(size_t)rowi*64 + d] = e / ssum;
}

// ---------------- K5: out[n, h*64+d] = softmax_a(q.agent * s) @ kvf ----------------
// Two-phase per 64-token tile: phase1 logits into P[a][n]; phase2 P @ kvf.
__global__ __launch_bounds__(1024, 4) void k_out(const float* __restrict__ qkv,
                                                 const float* __restrict__ agent,
                                                 const float* __restrict__ kvf,
                                                 float* __restrict__ out) {
    __shared__ __align__(16) float qt[64][68];
    __shared__ float P[256][65];
    __shared__ __align__(16) float kf[256][64];
    const int tile = blockIdx.x;   // 0..511
    const int h = blockIdx.y;
    const int t = threadIdx.x;
    const int a = t & 255;
    const int g = t >> 8;          // 0..3
    // load whole-head kvf into LDS (coalesced)
    {
        const float4* src = (const float4*)(kvf + (size_t)h*ANUM*DHEAD);
        float4* dst = (float4*)&kf[0][0];
        #pragma unroll
        for (int i = 0; i < 4; ++i) dst[t + i*1024] = src[t + i*1024];
    }
    // agent row in regs
    float ar[64];
    #pragma unroll
    for (int d4 = 0; d4 < 16; ++d4) {
        float4 v = *(const float4*)&agent[((size_t)h*ANUM + a)*DHEAD + d4*4];
        ar[d4*4+0]=v.x; ar[d4*4+1]=v.y; ar[d4*4+2]=v.z; ar[d4*4+3]=v.w;
    }
    const int lrow = t >> 4;        // 0..63
    const int lcol = (t & 15) * 4;
    const int n0 = tile * 64;
    float4 q4 = *(const float4*)&qkv[(size_t)(n0+lrow)*QKV_COLS + h*DHEAD + lcol];
    *(float4*)&qt[lrow][lcol] = q4;
    __syncthreads();
    // phase 1: thread (a, g): logits for n in [g*16, g*16+16)
    #pragma unroll
    for (int nn = 0; nn < 16; ++nn) {
        const int n = g*16 + nn;
        float l = 0.f;
        #pragma unroll
        for (int d4 = 0; d4 < 16; ++d4) {
            float4 v4 = *(const float4*)&qt[n][d4*4];
            l = fmaf(ar[d4*4+0], v4.x, l);
            l = fmaf(ar[d4*4+1], v4.y, l);
            l = fmaf(ar[d4*4+2], v4.z, l);
            l = fmaf(ar[d4*4+3], v4.w, l);
        }
        P[a][n] = __expf(l * SCALE_Q);
    }
    __syncthreads();
    // phase 2: thread (n = t&63, dg = t>>6): out slice of 4 d
    const int n = t & 63;
    const int dg = t >> 6;         // 0..15
    const int dd0 = dg * 4;
    float ax = 0.f, ay = 0.f, az = 0.f, aw = 0.f, s = 0.f;
    for (int aa = 0; aa < 256; ++aa) {
        float p = P[aa][n];
        s += p;
        float4 k4 = *(const float4*)&kf[aa][dd0];
        ax = fmaf(p, k4.x, ax); ay = fmaf(p, k4.y, ay);
        az = fmaf(p, k4.z, az); aw = fmaf(p, k4.w, aw);
    }
    const float inv = 1.f / s;
    *(float4*)&out[(size_t)(n0+n)*DIMX + h*DHEAD + dd0] =
        make_float4(ax*inv, ay*inv, az*inv, aw*inv);
}

extern "C" void kernel_launch(void* const* d_in, const int* in_sizes, int n_in,
                              void* d_out, int out_size, void* d_ws, size_t ws_size,
                              hipStream_t stream) {
    const float* x     = (const float*)d_in[0];
    const float* Wqkv  = (const float*)d_in[1];
    const float* agent = (const float*)d_in[2];
    const float* Wn    = (const float*)d_in[3];
    const float* bn    = (const float*)d_in[4];
    const float* Wm    = (const float*)d_in[5];
    const float* bm    = (const float*)d_in[6];
    const float* Wt    = (const float*)d_in[7];
    const float* bt    = (const float*)d_in[8];
    float* out = (float*)d_out;

    const size_t QKV_F  = (size_t)N_TOK * QKV_COLS;              // 50331648
    const size_t PACC_F = (size_t)NCHUNK * HEADS * ANUM * DHEAD; // 4194304
    const size_t PSUM_F = (size_t)NCHUNK * HEADS * ANUM;         // 65536
    const size_t KV_F   = (size_t)HEADS * ANUM * DHEAD;          // 131072
    const size_t need = (QKV_F + PACC_F + PSUM_F + 2*KV_F + 16) * sizeof(float);
    if (ws_size < need) return;

    float* ws   = (float*)d_ws;
    float* qkv  = ws;
    float* pacc = qkv + QKV_F;
    float* psum = pacc + PACC_F;
    float* kv   = psum + PSUM_F;
    float* kvf  = kv + KV_F;
    float* th   = kvf + KV_F;

    k_qkv   <<<dim3(QKV_COLS/128, N_TOK/128), 256, 0, stream>>>(x, Wqkv, qkv);
    k_kvagg <<<dim3(HEADS, NCHUNK),          1024, 0, stream>>>(qkv, agent, pacc, psum);
    k_combine<<<512,                          256, 0, stream>>>(pacc, psum, kv);
    k_thresh<<<1,                             256, 0, stream>>>(kv, Wt, bt, th);
    k_gate  <<<HEADS*ANUM,                     64, 0, stream>>>(kv, Wn, bn, Wm, bm, th, kvf);
    k_out   <<<dim3(N_TOK/64, HEADS),        1024, 0, stream>>>(qkv, agent, kvf, out);
}

// Round 5
// 1263.466 us; speedup vs baseline: 1.9803x; 1.2912x over previous
//
#include <hip/hip_runtime.h>
#include <hip/hip_bf16.h>
#include <math.h>

#define N_TOK 32768
#define DIMX 512
#define HEADS 8
#define DHEAD 64
#define ANUM 256
#define SCALE_Q 0.125f
#define KVCHUNK 1024
#define NCHUNK 32
#define STRIP 8192

typedef __bf16 v8bf __attribute__((ext_vector_type(8)));
typedef float v4f __attribute__((ext_vector_type(4)));

__device__ inline unsigned short f2bf(float f) {   // RTNE
    unsigned u = __float_as_uint(f);
    return (unsigned short)((u + 0x7fffu + ((u >> 16) & 1u)) >> 16);
}
__device__ inline float bf2f(unsigned short s) {
    return __uint_as_float((unsigned)s << 16);
}

// ---------------- K0: fp32 -> 3-way bf16 split (hi, mid, lo) ----------------
__global__ __launch_bounds__(256) void k_cvt3(const float* __restrict__ src,
                                              unsigned short* __restrict__ ph,
                                              unsigned short* __restrict__ pm,
                                              unsigned short* __restrict__ pl,
                                              int n4) {
    for (int i = blockIdx.x * 256 + threadIdx.x; i < n4; i += gridDim.x * 256) {
        float4 v = ((const float4*)src)[i];
        ushort4 H, M, L;
        {
            unsigned short h;
            h = f2bf(v.x); { float r1 = v.x - bf2f(h); unsigned short m = f2bf(r1);
                float r2 = r1 - bf2f(m); H.x = h; M.x = m; L.x = f2bf(r2); }
            h = f2bf(v.y); { float r1 = v.y - bf2f(h); unsigned short m = f2bf(r1);
                float r2 = r1 - bf2f(m); H.y = h; M.y = m; L.y = f2bf(r2); }
            h = f2bf(v.z); { float r1 = v.z - bf2f(h); unsigned short m = f2bf(r1);
                float r2 = r1 - bf2f(m); H.z = h; M.z = m; L.z = f2bf(r2); }
            h = f2bf(v.w); { float r1 = v.w - bf2f(h); unsigned short m = f2bf(r1);
                float r2 = r1 - bf2f(m); H.w = h; M.w = m; L.w = f2bf(r2); }
        }
        ((ushort4*)ph)[i] = H;
        ((ushort4*)pm)[i] = M;
        ((ushort4*)pl)[i] = L;
    }
}

// ---------------- K1: strip GEMM via split-bf16 MFMA ----------------
// 128x128 tile, 4 waves (2x2 of 64x64), K-step 32.
// q cols (j0<512): 3 terms (hh,hm,mh) -> bf16 out. k/v cols: 6 terms -> fp32 out.
// LDS chunk (row m, ks): byte = m*64 + ((ks ^ ((m>>1)&3))<<4)  (2-way max, free).
__global__ __launch_bounds__(256, 2) void k_gemm(
        const unsigned short* __restrict__ xh, const unsigned short* __restrict__ xm,
        const unsigned short* __restrict__ xl,
        const unsigned short* __restrict__ wh, const unsigned short* __restrict__ wm,
        const unsigned short* __restrict__ wl,
        unsigned short* __restrict__ qb, float* __restrict__ kvb, int mbase) {
    __shared__ __align__(16) unsigned short lds[6 * 4096];
    unsigned short* Ah = lds;
    unsigned short* Am = lds + 4096;
    unsigned short* Al = lds + 8192;
    unsigned short* Bh = lds + 12288;
    unsigned short* Bm = lds + 16384;
    unsigned short* Bl = lds + 20480;
    const int tid = threadIdx.x;
    const int lane = tid & 63;
    const int wid = tid >> 6;
    const int wr = wid >> 1;
    const int wc = wid & 1;
    const int mloc0 = blockIdx.y * 128;
    const int j0 = blockIdx.x * 128;
    const bool isQ = (j0 < 512);
    const int sm = tid >> 2;
    const int sk = tid & 3;
#define SWZ(row, ks) ((row) * 64 + (((ks) ^ (((row) >> 1) & 3)) << 4))
    const int so1 = SWZ(sm, sk);
    const int so2 = SWZ(sm + 64, sk);
    const size_t a1 = (size_t)(mloc0 + sm) * DIMX + sk * 8;
    const size_t a2 = a1 + (size_t)64 * DIMX;
    const size_t b1 = (size_t)(j0 + sm) * DIMX + sk * 8;
    const size_t b2 = b1 + (size_t)64 * DIMX;

    v4f acc[4][4];
    #pragma unroll
    for (int i = 0; i < 4; ++i)
        #pragma unroll
        for (int j = 0; j < 4; ++j)
            #pragma unroll
            for (int r = 0; r < 4; ++r) acc[i][j][r] = 0.0f;

    const int fm = lane & 15;
    const int fks = lane >> 4;
    int aofs[4], bofs[4];
    #pragma unroll
    for (int i = 0; i < 4; ++i) {
        const int am = wr * 64 + i * 16 + fm;
        const int bm = wc * 64 + i * 16 + fm;
        aofs[i] = SWZ(am, fks);
        bofs[i] = SWZ(bm, fks);
    }

    for (int k0 = 0; k0 < DIMX; k0 += 32) {
        uint4 ah1 = *(const uint4*)(xh + a1 + k0);
        uint4 ah2 = *(const uint4*)(xh + a2 + k0);
        uint4 am1 = *(const uint4*)(xm + a1 + k0);
        uint4 am2 = *(const uint4*)(xm + a2 + k0);
        uint4 bh1 = *(const uint4*)(wh + b1 + k0);
        uint4 bh2 = *(const uint4*)(wh + b2 + k0);
        uint4 bm1 = *(const uint4*)(wm + b1 + k0);
        uint4 bm2 = *(const uint4*)(wm + b2 + k0);
        uint4 al1, al2, bl1, bl2;
        if (!isQ) {
            al1 = *(const uint4*)(xl + a1 + k0);
            al2 = *(const uint4*)(xl + a2 + k0);
            bl1 = *(const uint4*)(wl + b1 + k0);
            bl2 = *(const uint4*)(wl + b2 + k0);
        }
        __syncthreads();
        *(uint4*)((char*)Ah + so1) = ah1;
        *(uint4*)((char*)Ah + so2) = ah2;
        *(uint4*)((char*)Am + so1) = am1;
        *(uint4*)((char*)Am + so2) = am2;
        *(uint4*)((char*)Bh + so1) = bh1;
        *(uint4*)((char*)Bh + so2) = bh2;
        *(uint4*)((char*)Bm + so1) = bm1;
        *(uint4*)((char*)Bm + so2) = bm2;
        if (!isQ) {
            *(uint4*)((char*)Al + so1) = al1;
            *(uint4*)((char*)Al + so2) = al2;
            *(uint4*)((char*)Bl + so1) = bl1;
            *(uint4*)((char*)Bl + so2) = bl2;
        }
        __syncthreads();
        v8bf fah[4], fbh[4];
        #pragma unroll
        for (int i = 0; i < 4; ++i) {
            fah[i] = *(const v8bf*)((const char*)Ah + aofs[i]);
            fbh[i] = *(const v8bf*)((const char*)Bh + bofs[i]);
        }
        #pragma unroll
        for (int mi = 0; mi < 4; ++mi)
            #pragma unroll
            for (int ni = 0; ni < 4; ++ni)
                acc[mi][ni] = __builtin_amdgcn_mfma_f32_16x16x32_bf16(fah[mi], fbh[ni], acc[mi][ni], 0, 0, 0);
        v8bf fam[4], fbm[4];
        #pragma unroll
        for (int i = 0; i < 4; ++i) {
            fam[i] = *(const v8bf*)((const char*)Am + aofs[i]);
            fbm[i] = *(const v8bf*)((const char*)Bm + bofs[i]);
        }
        #pragma unroll
        for (int mi = 0; mi < 4; ++mi)
            #pragma unroll
            for (int ni = 0; ni < 4; ++ni) {
                acc[mi][ni] = __builtin_amdgcn_mfma_f32_16x16x32_bf16(fah[mi], fbm[ni], acc[mi][ni], 0, 0, 0);
                acc[mi][ni] = __builtin_amdgcn_mfma_f32_16x16x32_bf16(fam[mi], fbh[ni], acc[mi][ni], 0, 0, 0);
            }
        if (!isQ) {
            #pragma unroll
            for (int mi = 0; mi < 4; ++mi)
                #pragma unroll
                for (int ni = 0; ni < 4; ++ni)
                    acc[mi][ni] = __builtin_amdgcn_mfma_f32_16x16x32_bf16(fam[mi], fbm[ni], acc[mi][ni], 0, 0, 0);
            v8bf fal[4], fbl[4];
            #pragma unroll
            for (int i = 0; i < 4; ++i) {
                fal[i] = *(const v8bf*)((const char*)Al + aofs[i]);
                fbl[i] = *(const v8bf*)((const char*)Bl + bofs[i]);
            }
            #pragma unroll
            for (int mi = 0; mi < 4; ++mi)
                #pragma unroll
                for (int ni = 0; ni < 4; ++ni) {
                    acc[mi][ni] = __builtin_amdgcn_mfma_f32_16x16x32_bf16(fah[mi], fbl[ni], acc[mi][ni], 0, 0, 0);
                    acc[mi][ni] = __builtin_amdgcn_mfma_f32_16x16x32_bf16(fal[mi], fbh[ni], acc[mi][ni], 0, 0, 0);
                }
        }
    }
#undef SWZ
    // C/D layout (m89-verified): col = lane&15, row = (lane>>4)*4 + reg
    const int crow = (lane >> 4) * 4;
    const int ccol = lane & 15;
    if (isQ) {
        #pragma unroll
        for (int mi = 0; mi < 4; ++mi)
            #pragma unroll
            for (int ni = 0; ni < 4; ++ni) {
                const int j = j0 + wc * 64 + ni * 16 + ccol;
                #pragma unroll
                for (int r = 0; r < 4; ++r) {
                    const int m = mbase + mloc0 + wr * 64 + mi * 16 + crow + r;
                    qb[(size_t)m * DIMX + j] = f2bf(acc[mi][ni][r]);
                }
            }
    } else {
        #pragma unroll
        for (int mi = 0; mi < 4; ++mi)
            #pragma unroll
            for (int ni = 0; ni < 4; ++ni) {
                const int j = j0 - 512 + wc * 64 + ni * 16 + ccol;
                #pragma unroll
                for (int r = 0; r < 4; ++r) {
                    const int m = mbase + mloc0 + wr * 64 + mi * 16 + crow + r;
                    kvb[(size_t)m * 1024 + j] = acc[mi][ni][r];
                }
            }
    }
}

// ---------------- K2: per (h, n-chunk) partial of softmax(agent.k over n) @ v ----------------
// kvb layout: [n][1024] = k cols 0..511 (h*64+d), v cols 512..1023.
__global__ __launch_bounds__(1024, 4) void k_kvagg(const float* __restrict__ kvb,
                                                   const float* __restrict__ agent,
                                                   float* __restrict__ pacc,
                                                   float* __restrict__ psum) {
    __shared__ __align__(16) float kt[64][68];
    __shared__ __align__(16) float vt[64][68];
    __shared__ float P[64][256];
    const int h = blockIdx.x;
    const int chunk = blockIdx.y;
    const int t = threadIdx.x;
    const int a = t & 255;
    const int g = t >> 8;
    const int d0 = g * 16;
    float ar[64];
    #pragma unroll
    for (int d4 = 0; d4 < 16; ++d4) {
        float4 v = *(const float4*)&agent[((size_t)h*ANUM + a)*DHEAD + d4*4];
        ar[d4*4+0]=v.x; ar[d4*4+1]=v.y; ar[d4*4+2]=v.z; ar[d4*4+3]=v.w;
    }
    float acc[16] = {};
    float s = 0.f;
    const int lrow = t >> 4;
    const int lcol = (t & 15) * 4;
    const int n0 = chunk * KVCHUNK;
    for (int nt = 0; nt < KVCHUNK; nt += 64) {
        const float* kb = kvb + (size_t)(n0+nt+lrow)*1024 + h*DHEAD + lcol;
        float4 k4g = *(const float4*)kb;
        float4 v4g = *(const float4*)(kb + 512);
        __syncthreads();
        *(float4*)&kt[lrow][lcol] = k4g;
        *(float4*)&vt[lrow][lcol] = v4g;
        __syncthreads();
        #pragma unroll
        for (int nn = 0; nn < 16; ++nn) {
            const int n = d0 + nn;
            float l = 0.f;
            #pragma unroll
            for (int d4 = 0; d4 < 16; ++d4) {
                float4 k4 = *(const float4*)&kt[n][d4*4];
                l = fmaf(ar[d4*4+0], k4.x, l);
                l = fmaf(ar[d4*4+1], k4.y, l);
                l = fmaf(ar[d4*4+2], k4.z, l);
                l = fmaf(ar[d4*4+3], k4.w, l);
            }
            P[n][a] = __expf(l - 20.f);
        }
        __syncthreads();
        for (int n = 0; n < 64; ++n) {
            float p = P[n][a];
            s += p;
            #pragma unroll
            for (int d4 = 0; d4 < 4; ++d4) {
                float4 v4 = *(const float4*)&vt[n][d0 + d4*4];
                acc[d4*4+0] = fmaf(p, v4.x, acc[d4*4+0]);
                acc[d4*4+1] = fmaf(p, v4.y, acc[d4*4+1]);
                acc[d4*4+2] = fmaf(p, v4.z, acc[d4*4+2]);
                acc[d4*4+3] = fmaf(p, v4.w, acc[d4*4+3]);
            }
        }
    }
    float* pa = pacc + ((size_t)chunk*HEADS + h)*(ANUM*DHEAD) + (size_t)a*DHEAD + d0;
    #pragma unroll
    for (int d4 = 0; d4 < 4; ++d4)
        *(float4*)&pa[d4*4] = make_float4(acc[d4*4], acc[d4*4+1], acc[d4*4+2], acc[d4*4+3]);
    if (g == 0) psum[((size_t)chunk*HEADS + h)*ANUM + a] = s;
}

// ---------------- K2b: combine chunk partials -> kv[h,a,d] ----------------
__global__ __launch_bounds__(256) void k_combine(const float* __restrict__ pacc,
                                                 const float* __restrict__ psum,
                                                 float* __restrict__ kv) {
    const int idx = blockIdx.x * 256 + threadIdx.x;
    const int ha = idx >> 6;
    float a = 0.f, s = 0.f;
    for (int c = 0; c < NCHUNK; ++c) {
        a += pacc[(size_t)c*131072 + idx];
        s += psum[c*2048 + ha];
    }
    kv[idx] = a / s;
}

// ---------------- K3: thresh = sigmoid(mean(kv_c @ Wt^T + bt)) ----------------
__global__ __launch_bounds__(256) void k_thresh(const float* __restrict__ kv,
                                                const float* __restrict__ Wt,
                                                const float* __restrict__ bt,
                                                float* __restrict__ th) {
    __shared__ float red[256];
    const int t = threadIdx.x;
    float s = 0.f;
    for (int i = t; i < HEADS*ANUM*DHEAD; i += 256)
        s += kv[i] * Wt[i & (DIMX-1)];
    red[t] = s;
    __syncthreads();
    for (int off = 128; off > 0; off >>= 1) {
        if (t < off) red[t] += red[t + off];
        __syncthreads();
    }
    if (t == 0) {
        float m = red[0] / (float)ANUM + bt[0];
        th[0] = 1.f / (1.f + expf(-m));
    }
}

// ---------------- K4: gating + row softmax over d ----------------
__global__ __launch_bounds__(64) void k_gate(const float* __restrict__ kv,
                                             const float* __restrict__ Wn,
                                             const float* __restrict__ bn,
                                             const float* __restrict__ Wm,
                                             const float* __restrict__ bm,
                                             const float* __restrict__ th,
                                             float* __restrict__ kvf) {
    const int rowi = blockIdx.x;
    const int d = threadIdx.x;
    __shared__ __align__(16) float r[64];
    r[d] = kv[(size_t)rowi*64 + d];
    __syncthreads();
    float sn = bn[d], sm = bm[d];
    #pragma unroll
    for (int j4 = 0; j4 < 16; ++j4) {
        float4 rr = *(const float4*)&r[j4*4];
        float4 w1 = *(const float4*)&Wn[d*64 + j4*4];
        float4 w2 = *(const float4*)&Wm[d*64 + j4*4];
        sn += rr.x*w1.x + rr.y*w1.y + rr.z*w1.z + rr.w*w1.w;
        sm += rr.x*w2.x + rr.y*w2.y + rr.z*w2.z + rr.w*w2.w;
    }
    float noise = 1.f/(1.f + __expf(-sn));
    float maskv = 1.f/(1.f + __expf(-sm));
    float tval = th[0];
    float val = r[d] * (maskv > tval ? 1.f : 0.f) + noise;
    float m = val;
    #pragma unroll
    for (int off = 32; off > 0; off >>= 1) m = fmaxf(m, __shfl_xor(m, off, 64));
    float e = __expf(val - m);
    float ssum = e;
    #pragma unroll
    for (int off = 32; off > 0; off >>= 1) ssum += __shfl_xor(ssum, off, 64);
    kvf[(size_t)rowi*64 + d] = e / ssum;
}

// ---------------- K5: out = softmax_a(q.agent * s) @ kvf  (q is bf16) ----------------
__global__ __launch_bounds__(1024, 4) void k_out(const unsigned short* __restrict__ qb,
                                                 const float* __restrict__ agent,
                                                 const float* __restrict__ kvf,
                                                 float* __restrict__ out) {
    __shared__ __align__(16) float qt[64][68];
    __shared__ float P[256][65];
    __shared__ __align__(16) float kf[256][64];
    const int tile = blockIdx.x;
    const int h = blockIdx.y;
    const int t = threadIdx.x;
    const int a = t & 255;
    const int g = t >> 8;
    {
        const float4* src = (const float4*)(kvf + (size_t)h*ANUM*DHEAD);
        float4* dst = (float4*)&kf[0][0];
        #pragma unroll
        for (int i = 0; i < 4; ++i) dst[t + i*1024] = src[t + i*1024];
    }
    float ar[64];
    #pragma unroll
    for (int d4 = 0; d4 < 16; ++d4) {
        float4 v = *(const float4*)&agent[((size_t)h*ANUM + a)*DHEAD + d4*4];
        ar[d4*4+0]=v.x; ar[d4*4+1]=v.y; ar[d4*4+2]=v.z; ar[d4*4+3]=v.w;
    }
    const int lrow = t >> 4;
    const int lcol = (t & 15) * 4;
    const int n0 = tile * 64;
    {
        ushort4 qu = *(const ushort4*)&qb[(size_t)(n0+lrow)*DIMX + h*DHEAD + lcol];
        qt[lrow][lcol+0] = bf2f(qu.x);
        qt[lrow][lcol+1] = bf2f(qu.y);
        qt[lrow][lcol+2] = bf2f(qu.z);
        qt[lrow][lcol+3] = bf2f(qu.w);
    }
    __syncthreads();
    #pragma unroll
    for (int nn = 0; nn < 16; ++nn) {
        const int n = g*16 + nn;
        float l = 0.f;
        #pragma unroll
        for (int d4 = 0; d4 < 16; ++d4) {
            float4 v4 = *(const float4*)&qt[n][d4*4];
            l = fmaf(ar[d4*4+0], v4.x, l);
            l = fmaf(ar[d4*4+1], v4.y, l);
            l = fmaf(ar[d4*4+2], v4.z, l);
            l = fmaf(ar[d4*4+3], v4.w, l);
        }
        P[a][n] = __expf(l * SCALE_Q);
    }
    __syncthreads();
    const int n = t & 63;
    const int dg = t >> 6;
    const int dd0 = dg * 4;
    float ax = 0.f, ay = 0.f, az = 0.f, aw = 0.f, s = 0.f;
    for (int aa = 0; aa < 256; ++aa) {
        float p = P[aa][n];
        s += p;
        float4 k4 = *(const float4*)&kf[aa][dd0];
        ax = fmaf(p, k4.x, ax); ay = fmaf(p, k4.y, ay);
        az = fmaf(p, k4.z, az); aw = fmaf(p, k4.w, aw);
    }
    const float inv = 1.f / s;
    *(float4*)&out[(size_t)(n0+n)*DIMX + h*DHEAD + dd0] =
        make_float4(ax*inv, ay*inv, az*inv, aw*inv);
}

extern "C" void kernel_launch(void* const* d_in, const int* in_sizes, int n_in,
                              void* d_out, int out_size, void* d_ws, size_t ws_size,
                              hipStream_t stream) {
    const float* x     = (const float*)d_in[0];
    const float* Wqkv  = (const float*)d_in[1];
    const float* agent = (const float*)d_in[2];
    const float* Wn    = (const float*)d_in[3];
    const float* bn    = (const float*)d_in[4];
    const float* Wm    = (const float*)d_in[5];
    const float* bm    = (const float*)d_in[6];
    const float* Wt    = (const float*)d_in[7];
    const float* bt    = (const float*)d_in[8];
    float* out = (float*)d_out;

    // workspace layout (total 215,744,576 B < r3-proven 219,414,592 B)
    const size_t KVB_F = (size_t)N_TOK * 1024;        // 33,554,432 floats
    const size_t QB_E  = (size_t)N_TOK * DIMX;        // 16,777,216 ushorts
    const size_t WSP_E = (size_t)3 * DIMX * DIMX;     // 786,432 ushorts per split
    const size_t XSP_E = (size_t)STRIP * DIMX;        // 4,194,304 ushorts per split
    const size_t PACC_F = (size_t)NCHUNK * HEADS * ANUM * DHEAD;  // 4,194,304
    const size_t PSUM_F = (size_t)NCHUNK * HEADS * ANUM;          // 65,536
    const size_t KV_F   = (size_t)HEADS * ANUM * DHEAD;           // 131,072

    char* p = (char*)d_ws;
    float* kvb = (float*)p;            p += KVB_F * 4;
    unsigned short* qbuf = (unsigned short*)p; p += QB_E * 2;
    unsigned short* wh = (unsigned short*)p;   p += WSP_E * 2;
    unsigned short* wm = (unsigned short*)p;   p += WSP_E * 2;
    unsigned short* wl = (unsigned short*)p;   p += WSP_E * 2;
    unsigned short* xh = (unsigned short*)p;   p += XSP_E * 2;
    unsigned short* xm = (unsigned short*)p;   p += XSP_E * 2;
    unsigned short* xl = (unsigned short*)p;   p += XSP_E * 2;
    float* pacc = (float*)p;           p += PACC_F * 4;
    float* psum = (float*)p;           p += PSUM_F * 4;
    float* kv   = (float*)p;           p += KV_F * 4;
    float* kvf  = (float*)p;           p += KV_F * 4;
    float* th   = (float*)p;           p += 64;
    if (ws_size < (size_t)(p - (char*)d_ws)) return;

    k_cvt3<<<768, 256, 0, stream>>>(Wqkv, wh, wm, wl, (int)(WSP_E / 4));
    for (int s = 0; s < N_TOK / STRIP; ++s) {
        k_cvt3<<<2048, 256, 0, stream>>>(x + (size_t)s * STRIP * DIMX, xh, xm, xl,
                                         (int)(XSP_E / 4));
        k_gemm<<<dim3(12, STRIP / 128), 256, 0, stream>>>(xh, xm, xl, wh, wm, wl,
                                                          qbuf, kvb, s * STRIP);
    }
    k_kvagg <<<dim3(HEADS, NCHUNK), 1024, 0, stream>>>(kvb, agent, pacc, psum);
    k_combine<<<512, 256, 0, stream>>>(pacc, psum, kv);
    k_thresh<<<1, 256, 0, stream>>>(kv, Wt, bt, th);
    k_gate  <<<HEADS*ANUM, 64, 0, stream>>>(kv, Wn, bn, Wm, bm, th, kvf);
    k_out   <<<dim3(N_TOK/64, HEADS), 1024, 0, stream>>>(qbuf, agent, kvf, out);
}

// Round 6
// 965.554 us; speedup vs baseline: 2.5913x; 1.3085x over previous
//
#include <hip/hip_runtime.h>
#include <hip/hip_bf16.h>
#include <math.h>

#define N_TOK 32768
#define DIMX 512
#define HEADS 8
#define DHEAD 64
#define ANUM 256
#define SCALE_Q 0.125f
#define KVCHUNK 1024
#define NCHUNK 32
#define STRIP 8192

typedef __bf16 v8bf __attribute__((ext_vector_type(8)));
typedef float v4f __attribute__((ext_vector_type(4)));

__device__ inline unsigned short f2bf(float f) {   // RTNE
    unsigned u = __float_as_uint(f);
    return (unsigned short)((u + 0x7fffu + ((u >> 16) & 1u)) >> 16);
}
__device__ inline float bf2f(unsigned short s) {
    return __uint_as_float((unsigned)s << 16);
}

// ---------------- K0: fp32 -> 3-way bf16 split (hi, mid, lo) ----------------
__global__ __launch_bounds__(256) void k_cvt3(const float* __restrict__ src,
                                              unsigned short* __restrict__ ph,
                                              unsigned short* __restrict__ pm,
                                              unsigned short* __restrict__ pl,
                                              int n4) {
    for (int i = blockIdx.x * 256 + threadIdx.x; i < n4; i += gridDim.x * 256) {
        float4 v = ((const float4*)src)[i];
        ushort4 H, M, L;
        {
            unsigned short h;
            h = f2bf(v.x); { float r1 = v.x - bf2f(h); unsigned short m = f2bf(r1);
                float r2 = r1 - bf2f(m); H.x = h; M.x = m; L.x = f2bf(r2); }
            h = f2bf(v.y); { float r1 = v.y - bf2f(h); unsigned short m = f2bf(r1);
                float r2 = r1 - bf2f(m); H.y = h; M.y = m; L.y = f2bf(r2); }
            h = f2bf(v.z); { float r1 = v.z - bf2f(h); unsigned short m = f2bf(r1);
                float r2 = r1 - bf2f(m); H.z = h; M.z = m; L.z = f2bf(r2); }
            h = f2bf(v.w); { float r1 = v.w - bf2f(h); unsigned short m = f2bf(r1);
                float r2 = r1 - bf2f(m); H.w = h; M.w = m; L.w = f2bf(r2); }
        }
        ((ushort4*)ph)[i] = H;
        ((ushort4*)pm)[i] = M;
        ((ushort4*)pl)[i] = L;
    }
}

// ---------------- K0b: fp32 -> 2-way bf16 split (hi, mid) ----------------
__global__ __launch_bounds__(256) void k_cvt2(const float* __restrict__ src,
                                              unsigned short* __restrict__ ph,
                                              unsigned short* __restrict__ pm,
                                              int n) {
    int i = blockIdx.x * 256 + threadIdx.x;
    if (i < n) {
        float v = src[i];
        unsigned short h = f2bf(v);
        ph[i] = h;
        pm[i] = f2bf(v - bf2f(h));
    }
}

// ---------------- K1: strip GEMM via split-bf16 MFMA ----------------
// 128x128 tile, 4 waves (2x2 of 64x64), K-step 32.
// q cols (j0<512): 3 terms (hh,hm,mh) -> bf16 out. k/v cols: 6 terms -> fp32 out.
__global__ __launch_bounds__(256, 2) void k_gemm(
        const unsigned short* __restrict__ xh, const unsigned short* __restrict__ xm,
        const unsigned short* __restrict__ xl,
        const unsigned short* __restrict__ wh, const unsigned short* __restrict__ wm,
        const unsigned short* __restrict__ wl,
        unsigned short* __restrict__ qb, float* __restrict__ kvb, int mbase) {
    __shared__ __align__(16) unsigned short lds[6 * 4096];
    unsigned short* Ah = lds;
    unsigned short* Am = lds + 4096;
    unsigned short* Al = lds + 8192;
    unsigned short* Bh = lds + 12288;
    unsigned short* Bm = lds + 16384;
    unsigned short* Bl = lds + 20480;
    const int tid = threadIdx.x;
    const int lane = tid & 63;
    const int wid = tid >> 6;
    const int wr = wid >> 1;
    const int wc = wid & 1;
    const int mloc0 = blockIdx.y * 128;
    const int j0 = blockIdx.x * 128;
    const bool isQ = (j0 < 512);
    const int sm = tid >> 2;
    const int sk = tid & 3;
#define SWZ(row, ks) ((row) * 64 + (((ks) ^ (((row) >> 1) & 3)) << 4))
    const int so1 = SWZ(sm, sk);
    const int so2 = SWZ(sm + 64, sk);
    const size_t a1 = (size_t)(mloc0 + sm) * DIMX + sk * 8;
    const size_t a2 = a1 + (size_t)64 * DIMX;
    const size_t b1 = (size_t)(j0 + sm) * DIMX + sk * 8;
    const size_t b2 = b1 + (size_t)64 * DIMX;

    v4f acc[4][4];
    #pragma unroll
    for (int i = 0; i < 4; ++i)
        #pragma unroll
        for (int j = 0; j < 4; ++j)
            #pragma unroll
            for (int r = 0; r < 4; ++r) acc[i][j][r] = 0.0f;

    const int fm = lane & 15;
    const int fks = lane >> 4;
    int aofs[4], bofs[4];
    #pragma unroll
    for (int i = 0; i < 4; ++i) {
        const int am = wr * 64 + i * 16 + fm;
        const int bm = wc * 64 + i * 16 + fm;
        aofs[i] = SWZ(am, fks);
        bofs[i] = SWZ(bm, fks);
    }

    for (int k0 = 0; k0 < DIMX; k0 += 32) {
        uint4 ah1 = *(const uint4*)(xh + a1 + k0);
        uint4 ah2 = *(const uint4*)(xh + a2 + k0);
        uint4 am1 = *(const uint4*)(xm + a1 + k0);
        uint4 am2 = *(const uint4*)(xm + a2 + k0);
        uint4 bh1 = *(const uint4*)(wh + b1 + k0);
        uint4 bh2 = *(const uint4*)(wh + b2 + k0);
        uint4 bm1 = *(const uint4*)(wm + b1 + k0);
        uint4 bm2 = *(const uint4*)(wm + b2 + k0);
        uint4 al1, al2, bl1, bl2;
        if (!isQ) {
            al1 = *(const uint4*)(xl + a1 + k0);
            al2 = *(const uint4*)(xl + a2 + k0);
            bl1 = *(const uint4*)(wl + b1 + k0);
            bl2 = *(const uint4*)(wl + b2 + k0);
        }
        __syncthreads();
        *(uint4*)((char*)Ah + so1) = ah1;
        *(uint4*)((char*)Ah + so2) = ah2;
        *(uint4*)((char*)Am + so1) = am1;
        *(uint4*)((char*)Am + so2) = am2;
        *(uint4*)((char*)Bh + so1) = bh1;
        *(uint4*)((char*)Bh + so2) = bh2;
        *(uint4*)((char*)Bm + so1) = bm1;
        *(uint4*)((char*)Bm + so2) = bm2;
        if (!isQ) {
            *(uint4*)((char*)Al + so1) = al1;
            *(uint4*)((char*)Al + so2) = al2;
            *(uint4*)((char*)Bl + so1) = bl1;
            *(uint4*)((char*)Bl + so2) = bl2;
        }
        __syncthreads();
        v8bf fah[4], fbh[4];
        #pragma unroll
        for (int i = 0; i < 4; ++i) {
            fah[i] = *(const v8bf*)((const char*)Ah + aofs[i]);
            fbh[i] = *(const v8bf*)((const char*)Bh + bofs[i]);
        }
        #pragma unroll
        for (int mi = 0; mi < 4; ++mi)
            #pragma unroll
            for (int ni = 0; ni < 4; ++ni)
                acc[mi][ni] = __builtin_amdgcn_mfma_f32_16x16x32_bf16(fah[mi], fbh[ni], acc[mi][ni], 0, 0, 0);
        v8bf fam[4], fbm[4];
        #pragma unroll
        for (int i = 0; i < 4; ++i) {
            fam[i] = *(const v8bf*)((const char*)Am + aofs[i]);
            fbm[i] = *(const v8bf*)((const char*)Bm + bofs[i]);
        }
        #pragma unroll
        for (int mi = 0; mi < 4; ++mi)
            #pragma unroll
            for (int ni = 0; ni < 4; ++ni) {
                acc[mi][ni] = __builtin_amdgcn_mfma_f32_16x16x32_bf16(fah[mi], fbm[ni], acc[mi][ni], 0, 0, 0);
                acc[mi][ni] = __builtin_amdgcn_mfma_f32_16x16x32_bf16(fam[mi], fbh[ni], acc[mi][ni], 0, 0, 0);
            }
        if (!isQ) {
            #pragma unroll
            for (int mi = 0; mi < 4; ++mi)
                #pragma unroll
                for (int ni = 0; ni < 4; ++ni)
                    acc[mi][ni] = __builtin_amdgcn_mfma_f32_16x16x32_bf16(fam[mi], fbm[ni], acc[mi][ni], 0, 0, 0);
            v8bf fal[4], fbl[4];
            #pragma unroll
            for (int i = 0; i < 4; ++i) {
                fal[i] = *(const v8bf*)((const char*)Al + aofs[i]);
                fbl[i] = *(const v8bf*)((const char*)Bl + bofs[i]);
            }
            #pragma unroll
            for (int mi = 0; mi < 4; ++mi)
                #pragma unroll
                for (int ni = 0; ni < 4; ++ni) {
                    acc[mi][ni] = __builtin_amdgcn_mfma_f32_16x16x32_bf16(fah[mi], fbl[ni], acc[mi][ni], 0, 0, 0);
                    acc[mi][ni] = __builtin_amdgcn_mfma_f32_16x16x32_bf16(fal[mi], fbh[ni], acc[mi][ni], 0, 0, 0);
                }
        }
    }
#undef SWZ
    const int crow = (lane >> 4) * 4;
    const int ccol = lane & 15;
    if (isQ) {
        #pragma unroll
        for (int mi = 0; mi < 4; ++mi)
            #pragma unroll
            for (int ni = 0; ni < 4; ++ni) {
                const int j = j0 + wc * 64 + ni * 16 + ccol;
                #pragma unroll
                for (int r = 0; r < 4; ++r) {
                    const int m = mbase + mloc0 + wr * 64 + mi * 16 + crow + r;
                    qb[(size_t)m * DIMX + j] = f2bf(acc[mi][ni][r]);
                }
            }
    } else {
        #pragma unroll
        for (int mi = 0; mi < 4; ++mi)
            #pragma unroll
            for (int ni = 0; ni < 4; ++ni) {
                const int j = j0 - 512 + wc * 64 + ni * 16 + ccol;
                #pragma unroll
                for (int r = 0; r < 4; ++r) {
                    const int m = mbase + mloc0 + wr * 64 + mi * 16 + crow + r;
                    kvb[(size_t)m * 1024 + j] = acc[mi][ni][r];
                }
            }
    }
}

// ---------------- K2: per (h, n-chunk) partial of softmax(agent.k over n) @ v ----------------
__global__ __launch_bounds__(1024, 4) void k_kvagg(const float* __restrict__ kvb,
                                                   const float* __restrict__ agent,
                                                   float* __restrict__ pacc,
                                                   float* __restrict__ psum) {
    __shared__ __align__(16) float kt[64][68];
    __shared__ __align__(16) float vt[64][68];
    __shared__ float P[64][256];
    const int h = blockIdx.x;
    const int chunk = blockIdx.y;
    const int t = threadIdx.x;
    const int a = t & 255;
    const int g = t >> 8;
    const int d0 = g * 16;
    float ar[64];
    #pragma unroll
    for (int d4 = 0; d4 < 16; ++d4) {
        float4 v = *(const float4*)&agent[((size_t)h*ANUM + a)*DHEAD + d4*4];
        ar[d4*4+0]=v.x; ar[d4*4+1]=v.y; ar[d4*4+2]=v.z; ar[d4*4+3]=v.w;
    }
    float acc[16] = {};
    float s = 0.f;
    const int lrow = t >> 4;
    const int lcol = (t & 15) * 4;
    const int n0 = chunk * KVCHUNK;
    for (int nt = 0; nt < KVCHUNK; nt += 64) {
        const float* kb = kvb + (size_t)(n0+nt+lrow)*1024 + h*DHEAD + lcol;
        float4 k4g = *(const float4*)kb;
        float4 v4g = *(const float4*)(kb + 512);
        __syncthreads();
        *(float4*)&kt[lrow][lcol] = k4g;
        *(float4*)&vt[lrow][lcol] = v4g;
        __syncthreads();
        #pragma unroll
        for (int nn = 0; nn < 16; ++nn) {
            const int n = d0 + nn;
            float l = 0.f;
            #pragma unroll
            for (int d4 = 0; d4 < 16; ++d4) {
                float4 k4 = *(const float4*)&kt[n][d4*4];
                l = fmaf(ar[d4*4+0], k4.x, l);
                l = fmaf(ar[d4*4+1], k4.y, l);
                l = fmaf(ar[d4*4+2], k4.z, l);
                l = fmaf(ar[d4*4+3], k4.w, l);
            }
            P[n][a] = __expf(l - 20.f);
        }
        __syncthreads();
        for (int n = 0; n < 64; ++n) {
            float p = P[n][a];
            s += p;
            #pragma unroll
            for (int d4 = 0; d4 < 4; ++d4) {
                float4 v4 = *(const float4*)&vt[n][d0 + d4*4];
                acc[d4*4+0] = fmaf(p, v4.x, acc[d4*4+0]);
                acc[d4*4+1] = fmaf(p, v4.y, acc[d4*4+1]);
                acc[d4*4+2] = fmaf(p, v4.z, acc[d4*4+2]);
                acc[d4*4+3] = fmaf(p, v4.w, acc[d4*4+3]);
            }
        }
    }
    float* pa = pacc + ((size_t)chunk*HEADS + h)*(ANUM*DHEAD) + (size_t)a*DHEAD + d0;
    #pragma unroll
    for (int d4 = 0; d4 < 4; ++d4)
        *(float4*)&pa[d4*4] = make_float4(acc[d4*4], acc[d4*4+1], acc[d4*4+2], acc[d4*4+3]);
    if (g == 0) psum[((size_t)chunk*HEADS + h)*ANUM + a] = s;
}

// ---------------- K2b: combine chunk partials -> kv[h,a,d] ----------------
__global__ __launch_bounds__(256) void k_combine(const float* __restrict__ pacc,
                                                 const float* __restrict__ psum,
                                                 float* __restrict__ kv) {
    const int idx = blockIdx.x * 256 + threadIdx.x;
    const int ha = idx >> 6;
    float a = 0.f, s = 0.f;
    for (int c = 0; c < NCHUNK; ++c) {
        a += pacc[(size_t)c*131072 + idx];
        s += psum[c*2048 + ha];
    }
    kv[idx] = a / s;
}

// ---------------- K3: thresh = sigmoid(mean(kv_c @ Wt^T + bt)) ----------------
__global__ __launch_bounds__(256) void k_thresh(const float* __restrict__ kv,
                                                const float* __restrict__ Wt,
                                                const float* __restrict__ bt,
                                                float* __restrict__ th) {
    __shared__ float red[256];
    const int t = threadIdx.x;
    float s = 0.f;
    for (int i = t; i < HEADS*ANUM*DHEAD; i += 256)
        s += kv[i] * Wt[i & (DIMX-1)];
    red[t] = s;
    __syncthreads();
    for (int off = 128; off > 0; off >>= 1) {
        if (t < off) red[t] += red[t + off];
        __syncthreads();
    }
    if (t == 0) {
        float m = red[0] / (float)ANUM + bt[0];
        th[0] = 1.f / (1.f + expf(-m));
    }
}

// ---------------- K4: gating + row softmax; writes TRANSPOSED split kvf ----------------
__global__ __launch_bounds__(64) void k_gate(const float* __restrict__ kv,
                                             const float* __restrict__ Wn,
                                             const float* __restrict__ bn,
                                             const float* __restrict__ Wm,
                                             const float* __restrict__ bm,
                                             const float* __restrict__ th,
                                             unsigned short* __restrict__ kth,
                                             unsigned short* __restrict__ ktm) {
    const int rowi = blockIdx.x;     // h*256+a
    const int d = threadIdx.x;
    __shared__ __align__(16) float r[64];
    r[d] = kv[(size_t)rowi*64 + d];
    __syncthreads();
    float sn = bn[d], sm = bm[d];
    #pragma unroll
    for (int j4 = 0; j4 < 16; ++j4) {
        float4 rr = *(const float4*)&r[j4*4];
        float4 w1 = *(const float4*)&Wn[d*64 + j4*4];
        float4 w2 = *(const float4*)&Wm[d*64 + j4*4];
        sn += rr.x*w1.x + rr.y*w1.y + rr.z*w1.z + rr.w*w1.w;
        sm += rr.x*w2.x + rr.y*w2.y + rr.z*w2.z + rr.w*w2.w;
    }
    float noise = 1.f/(1.f + __expf(-sn));
    float maskv = 1.f/(1.f + __expf(-sm));
    float tval = th[0];
    float val = r[d] * (maskv > tval ? 1.f : 0.f) + noise;
    float m = val;
    #pragma unroll
    for (int off = 32; off > 0; off >>= 1) m = fmaxf(m, __shfl_xor(m, off, 64));
    float e = __expf(val - m);
    float ssum = e;
    #pragma unroll
    for (int off = 32; off > 0; off >>= 1) ssum += __shfl_xor(ssum, off, 64);
    const float res = e / ssum;
    const int hh = rowi >> 8;
    const int a  = rowi & 255;
    unsigned short hb = f2bf(res);
    const size_t tix = ((size_t)hh * DHEAD + d) * ANUM + a;
    kth[tix] = hb;
    ktm[tix] = f2bf(res - bf2f(hb));
}

// ---------------- K5: out = softmax_a(q.agent*s) @ kvf via MFMA ----------------
// Block: 256 thr (4 waves), 64 tokens x 1 head. Wave w: S for agents w*64..+64.
// S: A=q bf16 (LDS, swizzled), B=agent hi+mid (global). exp fp32, exact row-sums
// via shfl butterfly. P stored single-bf16 in LDS (swizzled). PV: A=P, B=kvfT hi+mid.
__global__ __launch_bounds__(256, 3) void k_out_mfma(
        const unsigned short* __restrict__ qb,
        const unsigned short* __restrict__ agh, const unsigned short* __restrict__ agm,
        const unsigned short* __restrict__ kth, const unsigned short* __restrict__ ktm,
        float* __restrict__ out) {
    __shared__ __align__(16) unsigned short qt[64 * 64];    // [tok][d] swizzled
    __shared__ __align__(16) unsigned short P[64 * 256];    // [tok][agent] swizzled
    __shared__ float s_red[4][64];
    const int t = threadIdx.x;
    const int lane = t & 63;
    const int w = t >> 6;
    const int h = blockIdx.y;
    const int n0 = blockIdx.x * 64;
    // stage q tile (row stride 128B, chunk-XOR swizzle by (row&7)<<4)
    {
        const int row = t >> 2;
        const unsigned short* src = qb + (size_t)(n0 + row) * DIMX + h * DHEAD + (t & 3) * 16;
        uint4 v0 = *(const uint4*)src;
        uint4 v1 = *(const uint4*)(src + 8);
        const int b = row * 128 + (t & 3) * 32;
        const int sw = (row & 7) << 4;
        *(uint4*)((char*)qt + ((b) ^ sw)) = v0;
        *(uint4*)((char*)qt + ((b + 16) ^ sw)) = v1;
    }
    __syncthreads();
    const int fr = lane & 15;
    const int fc = lane >> 4;
    // ---- S phase ----
    v4f C[4][4];
    #pragma unroll
    for (int i = 0; i < 4; ++i)
        #pragma unroll
        for (int j = 0; j < 4; ++j)
            #pragma unroll
            for (int r = 0; r < 4; ++r) C[i][j][r] = 0.f;
    v8bf qa[4][2];
    #pragma unroll
    for (int mt = 0; mt < 4; ++mt) {
        const int tok = mt * 16 + fr;
        const int sw = (tok & 7) << 4;
        #pragma unroll
        for (int ks = 0; ks < 2; ++ks)
            qa[mt][ks] = *(const v8bf*)((const char*)qt + ((tok * 128 + fc * 16 + ks * 64) ^ sw));
    }
    const int a0w = w * 64;
    #pragma unroll
    for (int nt = 0; nt < 4; ++nt) {
        const size_t bix = ((size_t)h * ANUM + a0w + nt * 16 + fr) * DHEAD + fc * 8;
        v8bf B0h = *(const v8bf*)(agh + bix);
        v8bf B1h = *(const v8bf*)(agh + bix + 32);
        v8bf B0m = *(const v8bf*)(agm + bix);
        v8bf B1m = *(const v8bf*)(agm + bix + 32);
        #pragma unroll
        for (int mt = 0; mt < 4; ++mt) {
            C[mt][nt] = __builtin_amdgcn_mfma_f32_16x16x32_bf16(qa[mt][0], B0h, C[mt][nt], 0, 0, 0);
            C[mt][nt] = __builtin_amdgcn_mfma_f32_16x16x32_bf16(qa[mt][1], B1h, C[mt][nt], 0, 0, 0);
            C[mt][nt] = __builtin_amdgcn_mfma_f32_16x16x32_bf16(qa[mt][0], B0m, C[mt][nt], 0, 0, 0);
            C[mt][nt] = __builtin_amdgcn_mfma_f32_16x16x32_bf16(qa[mt][1], B1m, C[mt][nt], 0, 0, 0);
        }
    }
    // exp + exact row sums + store P (bf16, swizzled)
    #pragma unroll
    for (int mt = 0; mt < 4; ++mt)
        #pragma unroll
        for (int r = 0; r < 4; ++r) {
            const int tok = mt * 16 + fc * 4 + r;
            const int sw = (tok & 7) << 4;
            float pv[4];
            float sloc = 0.f;
            #pragma unroll
            for (int nt = 0; nt < 4; ++nt) {
                pv[nt] = __expf(C[mt][nt][r] * SCALE_Q);
                sloc += pv[nt];
            }
            #pragma unroll
            for (int m = 1; m < 16; m <<= 1) sloc += __shfl_xor(sloc, m, 64);
            if (fr == 0) s_red[w][tok] = sloc;
            #pragma unroll
            for (int nt = 0; nt < 4; ++nt) {
                const int ag = a0w + nt * 16 + fr;
                *(unsigned short*)((char*)P + ((tok * 512 + ag * 2) ^ sw)) = f2bf(pv[nt]);
            }
        }
    __syncthreads();
    // ---- PV phase: wave w handles tokens w*16..+16, all 64 d ----
    v4f D[4];
    #pragma unroll
    for (int i = 0; i < 4; ++i)
        #pragma unroll
        for (int r = 0; r < 4; ++r) D[i][r] = 0.f;
    const int tokA = w * 16 + fr;
    const int swA = (tokA & 7) << 4;
    #pragma unroll
    for (int ks = 0; ks < 8; ++ks) {
        v8bf pa = *(const v8bf*)((const char*)P + ((tokA * 512 + fc * 16 + ks * 64) ^ swA));
        #pragma unroll
        for (int nt = 0; nt < 4; ++nt) {
            const size_t bix = ((size_t)h * DHEAD + nt * 16 + fr) * ANUM + fc * 8 + ks * 32;
            v8bf vh = *(const v8bf*)(kth + bix);
            v8bf vm = *(const v8bf*)(ktm + bix);
            D[nt] = __builtin_amdgcn_mfma_f32_16x16x32_bf16(pa, vh, D[nt], 0, 0, 0);
            D[nt] = __builtin_amdgcn_mfma_f32_16x16x32_bf16(pa, vm, D[nt], 0, 0, 0);
        }
    }
    float inv[4];
    #pragma unroll
    for (int r = 0; r < 4; ++r) {
        const int tok = w * 16 + fc * 4 + r;
        inv[r] = 1.f / (s_red[0][tok] + s_red[1][tok] + s_red[2][tok] + s_red[3][tok]);
    }
    #pragma unroll
    for (int nt = 0; nt < 4; ++nt)
        #pragma unroll
        for (int r = 0; r < 4; ++r) {
            const int tok = w * 16 + fc * 4 + r;
            out[(size_t)(n0 + tok) * DIMX + h * DHEAD + nt * 16 + fr] = D[nt][r] * inv[r];
        }
}

extern "C" void kernel_launch(void* const* d_in, const int* in_sizes, int n_in,
                              void* d_out, int out_size, void* d_ws, size_t ws_size,
                              hipStream_t stream) {
    const float* x     = (const float*)d_in[0];
    const float* Wqkv  = (const float*)d_in[1];
    const float* agent = (const float*)d_in[2];
    const float* Wn    = (const float*)d_in[3];
    const float* bn    = (const float*)d_in[4];
    const float* Wm    = (const float*)d_in[5];
    const float* bm    = (const float*)d_in[6];
    const float* Wt    = (const float*)d_in[7];
    const float* bt    = (const float*)d_in[8];
    float* out = (float*)d_out;

    const size_t KVB_F = (size_t)N_TOK * 1024;
    const size_t QB_E  = (size_t)N_TOK * DIMX;
    const size_t WSP_E = (size_t)3 * DIMX * DIMX;
    const size_t XSP_E = (size_t)STRIP * DIMX;
    const size_t PACC_F = (size_t)NCHUNK * HEADS * ANUM * DHEAD;
    const size_t PSUM_F = (size_t)NCHUNK * HEADS * ANUM;
    const size_t KV_F   = (size_t)HEADS * ANUM * DHEAD;   // 131072

    char* p = (char*)d_ws;
    float* kvb = (float*)p;            p += KVB_F * 4;
    unsigned short* qbuf = (unsigned short*)p; p += QB_E * 2;
    unsigned short* wh = (unsigned short*)p;   p += WSP_E * 2;
    unsigned short* wm = (unsigned short*)p;   p += WSP_E * 2;
    unsigned short* wl = (unsigned short*)p;   p += WSP_E * 2;
    unsigned short* xh = (unsigned short*)p;   p += XSP_E * 2;
    unsigned short* xm = (unsigned short*)p;   p += XSP_E * 2;
    unsigned short* xl = (unsigned short*)p;   p += XSP_E * 2;
    float* pacc = (float*)p;           p += PACC_F * 4;
    float* psum = (float*)p;           p += PSUM_F * 4;
    float* kv   = (float*)p;           p += KV_F * 4;
    unsigned short* agh = (unsigned short*)p;  p += KV_F * 2;
    unsigned short* agm = (unsigned short*)p;  p += KV_F * 2;
    unsigned short* kth = (unsigned short*)p;  p += KV_F * 2;
    unsigned short* ktm = (unsigned short*)p;  p += KV_F * 2;
    float* th   = (float*)p;           p += 64;
    if (ws_size < (size_t)(p - (char*)d_ws)) return;

    k_cvt3<<<768, 256, 0, stream>>>(Wqkv, wh, wm, wl, (int)(WSP_E / 4));
    k_cvt2<<<(int)(KV_F / 256), 256, 0, stream>>>(agent, agh, agm, (int)KV_F);
    for (int s = 0; s < N_TOK / STRIP; ++s) {
        k_cvt3<<<2048, 256, 0, stream>>>(x + (size_t)s * STRIP * DIMX, xh, xm, xl,
                                         (int)(XSP_E / 4));
        k_gemm<<<dim3(12, STRIP / 128), 256, 0, stream>>>(xh, xm, xl, wh, wm, wl,
                                                          qbuf, kvb, s * STRIP);
    }
    k_kvagg <<<dim3(HEADS, NCHUNK), 1024, 0, stream>>>(kvb, agent, pacc, psum);
    k_combine<<<512, 256, 0, stream>>>(pacc, psum, kv);
    k_thresh<<<1, 256, 0, stream>>>(kv, Wt, bt, th);
    k_gate  <<<HEADS*ANUM, 64, 0, stream>>>(kv, Wn, bn, Wm, bm, th, kth, ktm);
    k_out_mfma<<<dim3(N_TOK/64, HEADS), 256, 0, stream>>>(qbuf, agh, agm, kth, ktm, out);
}

// Round 7
// 736.803 us; speedup vs baseline: 3.3958x; 1.3105x over previous
//
#include <hip/hip_runtime.h>
#include <hip/hip_bf16.h>
#include <math.h>

#define N_TOK 32768
#define DIMX 512
#define HEADS 8
#define DHEAD 64
#define ANUM 256
#define SCALE_Q 0.125f
#define KVCHUNK 1024
#define NCHUNK 32
#define STRIP 8192

typedef __bf16 v8bf __attribute__((ext_vector_type(8)));
typedef float v4f __attribute__((ext_vector_type(4)));

__device__ inline unsigned short f2bf(float f) {   // RTNE
    unsigned u = __float_as_uint(f);
    return (unsigned short)((u + 0x7fffu + ((u >> 16) & 1u)) >> 16);
}
__device__ inline float bf2f(unsigned short s) {
    return __uint_as_float((unsigned)s << 16);
}

// ---------------- K0: fp32 -> 3-way bf16 split (hi, mid, lo) ----------------
__global__ __launch_bounds__(256) void k_cvt3(const float* __restrict__ src,
                                              unsigned short* __restrict__ ph,
                                              unsigned short* __restrict__ pm,
                                              unsigned short* __restrict__ pl,
                                              int n4) {
    for (int i = blockIdx.x * 256 + threadIdx.x; i < n4; i += gridDim.x * 256) {
        float4 v = ((const float4*)src)[i];
        ushort4 H, M, L;
        {
            unsigned short h;
            h = f2bf(v.x); { float r1 = v.x - bf2f(h); unsigned short m = f2bf(r1);
                float r2 = r1 - bf2f(m); H.x = h; M.x = m; L.x = f2bf(r2); }
            h = f2bf(v.y); { float r1 = v.y - bf2f(h); unsigned short m = f2bf(r1);
                float r2 = r1 - bf2f(m); H.y = h; M.y = m; L.y = f2bf(r2); }
            h = f2bf(v.z); { float r1 = v.z - bf2f(h); unsigned short m = f2bf(r1);
                float r2 = r1 - bf2f(m); H.z = h; M.z = m; L.z = f2bf(r2); }
            h = f2bf(v.w); { float r1 = v.w - bf2f(h); unsigned short m = f2bf(r1);
                float r2 = r1 - bf2f(m); H.w = h; M.w = m; L.w = f2bf(r2); }
        }
        ((ushort4*)ph)[i] = H;
        ((ushort4*)pm)[i] = M;
        ((ushort4*)pl)[i] = L;
    }
}

// ---------------- K1: strip GEMM via split-bf16 MFMA ----------------
// q (j0<512): 3 terms -> bf16 out. k (512..1023): 6 terms -> fp32 [N][512].
// v (>=1024): 6 terms -> hi/mid bf16 [N][512].
__global__ __launch_bounds__(256, 2) void k_gemm(
        const unsigned short* __restrict__ xh, const unsigned short* __restrict__ xm,
        const unsigned short* __restrict__ xl,
        const unsigned short* __restrict__ wh, const unsigned short* __restrict__ wm,
        const unsigned short* __restrict__ wl,
        unsigned short* __restrict__ qb, float* __restrict__ kvb,
        unsigned short* __restrict__ vhg, unsigned short* __restrict__ vmg, int mbase) {
    __shared__ __align__(16) unsigned short lds[6 * 4096];
    unsigned short* Ah = lds;
    unsigned short* Am = lds + 4096;
    unsigned short* Al = lds + 8192;
    unsigned short* Bh = lds + 12288;
    unsigned short* Bm = lds + 16384;
    unsigned short* Bl = lds + 20480;
    const int tid = threadIdx.x;
    const int lane = tid & 63;
    const int wid = tid >> 6;
    const int wr = wid >> 1;
    const int wc = wid & 1;
    const int mloc0 = blockIdx.y * 128;
    const int j0 = blockIdx.x * 128;
    const bool isQ = (j0 < 512);
    const int sm = tid >> 2;
    const int sk = tid & 3;
#define SWZ(row, ks) ((row) * 64 + (((ks) ^ (((row) >> 1) & 3)) << 4))
    const int so1 = SWZ(sm, sk);
    const int so2 = SWZ(sm + 64, sk);
    const size_t a1 = (size_t)(mloc0 + sm) * DIMX + sk * 8;
    const size_t a2 = a1 + (size_t)64 * DIMX;
    const size_t b1 = (size_t)(j0 + sm) * DIMX + sk * 8;
    const size_t b2 = b1 + (size_t)64 * DIMX;

    v4f acc[4][4];
    #pragma unroll
    for (int i = 0; i < 4; ++i)
        #pragma unroll
        for (int j = 0; j < 4; ++j)
            #pragma unroll
            for (int r = 0; r < 4; ++r) acc[i][j][r] = 0.0f;

    const int fm = lane & 15;
    const int fks = lane >> 4;
    int aofs[4], bofs[4];
    #pragma unroll
    for (int i = 0; i < 4; ++i) {
        const int am = wr * 64 + i * 16 + fm;
        const int bm = wc * 64 + i * 16 + fm;
        aofs[i] = SWZ(am, fks);
        bofs[i] = SWZ(bm, fks);
    }

    for (int k0 = 0; k0 < DIMX; k0 += 32) {
        uint4 ah1 = *(const uint4*)(xh + a1 + k0);
        uint4 ah2 = *(const uint4*)(xh + a2 + k0);
        uint4 am1 = *(const uint4*)(xm + a1 + k0);
        uint4 am2 = *(const uint4*)(xm + a2 + k0);
        uint4 bh1 = *(const uint4*)(wh + b1 + k0);
        uint4 bh2 = *(const uint4*)(wh + b2 + k0);
        uint4 bm1 = *(const uint4*)(wm + b1 + k0);
        uint4 bm2 = *(const uint4*)(wm + b2 + k0);
        uint4 al1, al2, bl1, bl2;
        if (!isQ) {
            al1 = *(const uint4*)(xl + a1 + k0);
            al2 = *(const uint4*)(xl + a2 + k0);
            bl1 = *(const uint4*)(wl + b1 + k0);
            bl2 = *(const uint4*)(wl + b2 + k0);
        }
        __syncthreads();
        *(uint4*)((char*)Ah + so1) = ah1;
        *(uint4*)((char*)Ah + so2) = ah2;
        *(uint4*)((char*)Am + so1) = am1;
        *(uint4*)((char*)Am + so2) = am2;
        *(uint4*)((char*)Bh + so1) = bh1;
        *(uint4*)((char*)Bh + so2) = bh2;
        *(uint4*)((char*)Bm + so1) = bm1;
        *(uint4*)((char*)Bm + so2) = bm2;
        if (!isQ) {
            *(uint4*)((char*)Al + so1) = al1;
            *(uint4*)((char*)Al + so2) = al2;
            *(uint4*)((char*)Bl + so1) = bl1;
            *(uint4*)((char*)Bl + so2) = bl2;
        }
        __syncthreads();
        v8bf fah[4], fbh[4];
        #pragma unroll
        for (int i = 0; i < 4; ++i) {
            fah[i] = *(const v8bf*)((const char*)Ah + aofs[i]);
            fbh[i] = *(const v8bf*)((const char*)Bh + bofs[i]);
        }
        #pragma unroll
        for (int mi = 0; mi < 4; ++mi)
            #pragma unroll
            for (int ni = 0; ni < 4; ++ni)
                acc[mi][ni] = __builtin_amdgcn_mfma_f32_16x16x32_bf16(fah[mi], fbh[ni], acc[mi][ni], 0, 0, 0);
        v8bf fam[4], fbm[4];
        #pragma unroll
        for (int i = 0; i < 4; ++i) {
            fam[i] = *(const v8bf*)((const char*)Am + aofs[i]);
            fbm[i] = *(const v8bf*)((const char*)Bm + bofs[i]);
        }
        #pragma unroll
        for (int mi = 0; mi < 4; ++mi)
            #pragma unroll
            for (int ni = 0; ni < 4; ++ni) {
                acc[mi][ni] = __builtin_amdgcn_mfma_f32_16x16x32_bf16(fah[mi], fbm[ni], acc[mi][ni], 0, 0, 0);
                acc[mi][ni] = __builtin_amdgcn_mfma_f32_16x16x32_bf16(fam[mi], fbh[ni], acc[mi][ni], 0, 0, 0);
            }
        if (!isQ) {
            #pragma unroll
            for (int mi = 0; mi < 4; ++mi)
                #pragma unroll
                for (int ni = 0; ni < 4; ++ni)
                    acc[mi][ni] = __builtin_amdgcn_mfma_f32_16x16x32_bf16(fam[mi], fbm[ni], acc[mi][ni], 0, 0, 0);
            v8bf fal[4], fbl[4];
            #pragma unroll
            for (int i = 0; i < 4; ++i) {
                fal[i] = *(const v8bf*)((const char*)Al + aofs[i]);
                fbl[i] = *(const v8bf*)((const char*)Bl + bofs[i]);
            }
            #pragma unroll
            for (int mi = 0; mi < 4; ++mi)
                #pragma unroll
                for (int ni = 0; ni < 4; ++ni) {
                    acc[mi][ni] = __builtin_amdgcn_mfma_f32_16x16x32_bf16(fah[mi], fbl[ni], acc[mi][ni], 0, 0, 0);
                    acc[mi][ni] = __builtin_amdgcn_mfma_f32_16x16x32_bf16(fal[mi], fbh[ni], acc[mi][ni], 0, 0, 0);
                }
        }
    }
#undef SWZ
    const int crow = (lane >> 4) * 4;
    const int ccol = lane & 15;
    if (isQ) {
        #pragma unroll
        for (int mi = 0; mi < 4; ++mi)
            #pragma unroll
            for (int ni = 0; ni < 4; ++ni) {
                const int j = j0 + wc * 64 + ni * 16 + ccol;
                #pragma unroll
                for (int r = 0; r < 4; ++r) {
                    const int m = mbase + mloc0 + wr * 64 + mi * 16 + crow + r;
                    qb[(size_t)m * DIMX + j] = f2bf(acc[mi][ni][r]);
                }
            }
    } else if (j0 < 1024) {  // k -> fp32 [N][512]
        #pragma unroll
        for (int mi = 0; mi < 4; ++mi)
            #pragma unroll
            for (int ni = 0; ni < 4; ++ni) {
                const int j = j0 - 512 + wc * 64 + ni * 16 + ccol;
                #pragma unroll
                for (int r = 0; r < 4; ++r) {
                    const int m = mbase + mloc0 + wr * 64 + mi * 16 + crow + r;
                    kvb[(size_t)m * 512 + j] = acc[mi][ni][r];
                }
            }
    } else {                 // v -> hi/mid bf16 [N][512]
        #pragma unroll
        for (int mi = 0; mi < 4; ++mi)
            #pragma unroll
            for (int ni = 0; ni < 4; ++ni) {
                const int j = j0 - 1024 + wc * 64 + ni * 16 + ccol;
                #pragma unroll
                for (int r = 0; r < 4; ++r) {
                    const int m = mbase + mloc0 + wr * 64 + mi * 16 + crow + r;
                    const float val = acc[mi][ni][r];
                    const unsigned short hb = f2bf(val);
                    vhg[(size_t)m * 512 + j] = hb;
                    vmg[(size_t)m * 512 + j] = f2bf(val - bf2f(hb));
                }
            }
    }
}

// ---------------- K2: MFMA kv-aggregation ----------------
// Block (h, chunk=1024 tok), 512 thr / 8 waves; wave owns 32 agents.
// Per 32-tok subtile: k fp32->3x bf16 LDS; S = agent(3way) x k (6 terms);
// exp fp32 + exact shfl row-sums; P hi/mid bf16 LDS (per wave);
// kvacc += P x v (v hi/mid from global, transposed in LDS; 4 terms).
__global__ __launch_bounds__(512, 1) void k_kvagg(
        const float* __restrict__ kvb,
        const unsigned short* __restrict__ vhg, const unsigned short* __restrict__ vmg,
        const unsigned short* __restrict__ agh, const unsigned short* __restrict__ agm,
        const unsigned short* __restrict__ agl,
        float* __restrict__ pacc, float* __restrict__ psum) {
    // LDS map (bytes): k hi/mi/lo 3x4096 | vT hi/mi 2x8192 | P 8 waves x (2x2048)
    __shared__ __align__(16) char S[61440];
    const int h = blockIdx.x, chunk = blockIdx.y;
    const int t = threadIdx.x, lane = t & 63, w = t >> 6;
    const int fr = lane & 15, fc = lane >> 4;
    const int n0 = chunk * KVCHUNK;
    // agent fragments (loop-invariant): row a = ..+fr, k d = ks*32 + fc*8
    v8bf agf[3][2][2];
    #pragma unroll
    for (int mt = 0; mt < 2; ++mt)
        #pragma unroll
        for (int ks = 0; ks < 2; ++ks) {
            const size_t ix = ((size_t)(h * ANUM + w * 32 + mt * 16 + fr)) * 64 + ks * 32 + fc * 8;
            agf[0][mt][ks] = *(const v8bf*)(agh + ix);
            agf[1][mt][ks] = *(const v8bf*)(agm + ix);
            agf[2][mt][ks] = *(const v8bf*)(agl + ix);
        }
    const int cn = t >> 4;           // 0..31 (subtile row)
    const int cd0 = (t & 15) * 4;    // 0..60 (d quad)
    float4 kreg; ushort4 vhr, vmr;
    {
        const size_t gix = ((size_t)(n0 + cn)) * 512 + h * 64 + cd0;
        kreg = *(const float4*)(kvb + gix);
        vhr = *(const ushort4*)(vhg + gix);
        vmr = *(const ushort4*)(vmg + gix);
    }
    v4f kvacc[2][4];
    #pragma unroll
    for (int mt = 0; mt < 2; ++mt)
        #pragma unroll
        for (int nt = 0; nt < 4; ++nt)
            #pragma unroll
            for (int r = 0; r < 4; ++r) kvacc[mt][nt][r] = 0.f;
    float sacc[2][4] = {{0.f,0.f,0.f,0.f},{0.f,0.f,0.f,0.f}};

    for (int it = 0; it < 32; ++it) {
        __syncthreads();
        // --- stage k splits (row-major [32][64], 128B rows, XOR swz) ---
        {
            ushort4 H, M, L;
            unsigned short hh;
            hh = f2bf(kreg.x); { float r1 = kreg.x - bf2f(hh); M.x = f2bf(r1);
                L.x = f2bf(r1 - bf2f(M.x)); H.x = hh; }
            hh = f2bf(kreg.y); { float r1 = kreg.y - bf2f(hh); M.y = f2bf(r1);
                L.y = f2bf(r1 - bf2f(M.y)); H.y = hh; }
            hh = f2bf(kreg.z); { float r1 = kreg.z - bf2f(hh); M.z = f2bf(r1);
                L.z = f2bf(r1 - bf2f(M.z)); H.z = hh; }
            hh = f2bf(kreg.w); { float r1 = kreg.w - bf2f(hh); M.w = f2bf(r1);
                L.w = f2bf(r1 - bf2f(M.w)); H.w = hh; }
            const int kb0 = cn * 128 + ((cd0 * 2) ^ ((cn & 7) << 4));
            *(ushort4*)(S + kb0) = H;
            *(ushort4*)(S + 4096 + kb0) = M;
            *(ushort4*)(S + 8192 + kb0) = L;
            // --- stage vT splits ([64 d][128B rows], XOR swz) ---
            const unsigned short vh4[4] = {vhr.x, vhr.y, vhr.z, vhr.w};
            const unsigned short vm4[4] = {vmr.x, vmr.y, vmr.z, vmr.w};
            #pragma unroll
            for (int i = 0; i < 4; ++i) {
                const int d = cd0 + i;
                const int vb = d * 128 + ((cn * 2) ^ ((d & 7) << 4));
                *(unsigned short*)(S + 12288 + vb) = vh4[i];
                *(unsigned short*)(S + 20480 + vb) = vm4[i];
            }
        }
        if (it < 31) {  // prefetch next subtile
            const size_t gix = ((size_t)(n0 + (it + 1) * 32 + cn)) * 512 + h * 64 + cd0;
            kreg = *(const float4*)(kvb + gix);
            vhr = *(const ushort4*)(vhg + gix);
            vmr = *(const ushort4*)(vmg + gix);
        }
        __syncthreads();
        // --- phase A: S[a][n] (6 terms) ---
        v4f C[2][2];
        #pragma unroll
        for (int mt = 0; mt < 2; ++mt)
            #pragma unroll
            for (int nt = 0; nt < 2; ++nt)
                #pragma unroll
                for (int r = 0; r < 4; ++r) C[mt][nt][r] = 0.f;
        #pragma unroll
        for (int ks = 0; ks < 2; ++ks) {
            v8bf kb[3][2];
            #pragma unroll
            for (int nt = 0; nt < 2; ++nt) {
                const int row = nt * 16 + fr;
                const int off = row * 128 + ((ks * 64 + fc * 16) ^ ((row & 7) << 4));
                kb[0][nt] = *(const v8bf*)(S + off);
                kb[1][nt] = *(const v8bf*)(S + 4096 + off);
                kb[2][nt] = *(const v8bf*)(S + 8192 + off);
            }
            #pragma unroll
            for (int mt = 0; mt < 2; ++mt)
                #pragma unroll
                for (int nt = 0; nt < 2; ++nt) {
                    C[mt][nt] = __builtin_amdgcn_mfma_f32_16x16x32_bf16(agf[0][mt][ks], kb[0][nt], C[mt][nt], 0, 0, 0);
                    C[mt][nt] = __builtin_amdgcn_mfma_f32_16x16x32_bf16(agf[0][mt][ks], kb[1][nt], C[mt][nt], 0, 0, 0);
                    C[mt][nt] = __builtin_amdgcn_mfma_f32_16x16x32_bf16(agf[1][mt][ks], kb[0][nt], C[mt][nt], 0, 0, 0);
                    C[mt][nt] = __builtin_amdgcn_mfma_f32_16x16x32_bf16(agf[1][mt][ks], kb[1][nt], C[mt][nt], 0, 0, 0);
                    C[mt][nt] = __builtin_amdgcn_mfma_f32_16x16x32_bf16(agf[0][mt][ks], kb[2][nt], C[mt][nt], 0, 0, 0);
                    C[mt][nt] = __builtin_amdgcn_mfma_f32_16x16x32_bf16(agf[2][mt][ks], kb[0][nt], C[mt][nt], 0, 0, 0);
                }
        }
        // --- exp + P (hi/mid) + exact row sums ---
        const int pbase = 28672 + w * 4096;
        #pragma unroll
        for (int mt = 0; mt < 2; ++mt) {
            float sl[4] = {0.f, 0.f, 0.f, 0.f};
            #pragma unroll
            for (int nt = 0; nt < 2; ++nt)
                #pragma unroll
                for (int r = 0; r < 4; ++r) {
                    const float pv = __expf(C[mt][nt][r] - 20.f);
                    sl[r] += pv;
                    const unsigned short ph = f2bf(pv);
                    const unsigned short pmv = f2bf(pv - bf2f(ph));
                    const int a = mt * 16 + fc * 4 + r;
                    const int off = pbase + a * 64 + (((nt * 16 + fr) * 2) ^ ((a & 3) << 4));
                    *(unsigned short*)(S + off) = ph;
                    *(unsigned short*)(S + off + 2048) = pmv;
                }
            #pragma unroll
            for (int r = 0; r < 4; ++r) {
                float v = sl[r];
                v += __shfl_xor(v, 1, 64); v += __shfl_xor(v, 2, 64);
                v += __shfl_xor(v, 4, 64); v += __shfl_xor(v, 8, 64);
                sacc[mt][r] += v;
            }
        }
        // --- phase B: kvacc += P x v (4 terms) ---
        v8bf pah[2], pam[2];
        #pragma unroll
        for (int mt = 0; mt < 2; ++mt) {
            const int a = mt * 16 + fr;
            const int off = pbase + a * 64 + ((fc * 16) ^ ((a & 3) << 4));
            pah[mt] = *(const v8bf*)(S + off);
            pam[mt] = *(const v8bf*)(S + off + 2048);
        }
        #pragma unroll
        for (int nt = 0; nt < 4; ++nt) {
            const int d = nt * 16 + fr;
            const int off = 12288 + d * 128 + ((fc * 16) ^ ((d & 7) << 4));
            v8bf vbh = *(const v8bf*)(S + off);
            v8bf vbm = *(const v8bf*)(S + off + 8192);
            #pragma unroll
            for (int mt = 0; mt < 2; ++mt) {
                kvacc[mt][nt] = __builtin_amdgcn_mfma_f32_16x16x32_bf16(pah[mt], vbh, kvacc[mt][nt], 0, 0, 0);
                kvacc[mt][nt] = __builtin_amdgcn_mfma_f32_16x16x32_bf16(pah[mt], vbm, kvacc[mt][nt], 0, 0, 0);
                kvacc[mt][nt] = __builtin_amdgcn_mfma_f32_16x16x32_bf16(pam[mt], vbh, kvacc[mt][nt], 0, 0, 0);
                kvacc[mt][nt] = __builtin_amdgcn_mfma_f32_16x16x32_bf16(pam[mt], vbm, kvacc[mt][nt], 0, 0, 0);
            }
        }
    }
    // --- epilogue ---
    const size_t base = (size_t)chunk * HEADS + h;
    #pragma unroll
    for (int mt = 0; mt < 2; ++mt)
        #pragma unroll
        for (int r = 0; r < 4; ++r)
            if (fr == 0)
                psum[base * ANUM + w * 32 + mt * 16 + fc * 4 + r] = sacc[mt][r];
    #pragma unroll
    for (int mt = 0; mt < 2; ++mt)
        #pragma unroll
        for (int nt = 0; nt < 4; ++nt)
            #pragma unroll
            for (int r = 0; r < 4; ++r)
                pacc[base * (ANUM * DHEAD) +
                     (size_t)(w * 32 + mt * 16 + fc * 4 + r) * 64 + nt * 16 + fr] =
                    kvacc[mt][nt][r];
}

// ---------------- K2b: combine chunk partials -> kv[h,a,d] ----------------
__global__ __launch_bounds__(256) void k_combine(const float* __restrict__ pacc,
                                                 const float* __restrict__ psum,
                                                 float* __restrict__ kv) {
    const int idx = blockIdx.x * 256 + threadIdx.x;
    const int ha = idx >> 6;
    float a = 0.f, s = 0.f;
    for (int c = 0; c < NCHUNK; ++c) {
        a += pacc[(size_t)c*131072 + idx];
        s += psum[c*2048 + ha];
    }
    kv[idx] = a / s;
}

// ---------------- K3: thresh = sigmoid(mean(kv_c @ Wt^T + bt)) ----------------
__global__ __launch_bounds__(256) void k_thresh(const float* __restrict__ kv,
                                                const float* __restrict__ Wt,
                                                const float* __restrict__ bt,
                                                float* __restrict__ th) {
    __shared__ float red[256];
    const int t = threadIdx.x;
    float s = 0.f;
    for (int i = t; i < HEADS*ANUM*DHEAD; i += 256)
        s += kv[i] * Wt[i & (DIMX-1)];
    red[t] = s;
    __syncthreads();
    for (int off = 128; off > 0; off >>= 1) {
        if (t < off) red[t] += red[t + off];
        __syncthreads();
    }
    if (t == 0) {
        float m = red[0] / (float)ANUM + bt[0];
        th[0] = 1.f / (1.f + expf(-m));
    }
}

// ---------------- K4: gating + row softmax; writes TRANSPOSED split kvf ----------------
__global__ __launch_bounds__(64) void k_gate(const float* __restrict__ kv,
                                             const float* __restrict__ Wn,
                                             const float* __restrict__ bn,
                                             const float* __restrict__ Wm,
                                             const float* __restrict__ bm,
                                             const float* __restrict__ th,
                                             unsigned short* __restrict__ kth,
                                             unsigned short* __restrict__ ktm) {
    const int rowi = blockIdx.x;     // h*256+a
    const int d = threadIdx.x;
    __shared__ __align__(16) float r[64];
    r[d] = kv[(size_t)rowi*64 + d];
    __syncthreads();
    float sn = bn[d], sm = bm[d];
    #pragma unroll
    for (int j4 = 0; j4 < 16; ++j4) {
        float4 rr = *(const float4*)&r[j4*4];
        float4 w1 = *(const float4*)&Wn[d*64 + j4*4];
        float4 w2 = *(const float4*)&Wm[d*64 + j4*4];
        sn += rr.x*w1.x + rr.y*w1.y + rr.z*w1.z + rr.w*w1.w;
        sm += rr.x*w2.x + rr.y*w2.y + rr.z*w2.z + rr.w*w2.w;
    }
    float noise = 1.f/(1.f + __expf(-sn));
    float maskv = 1.f/(1.f + __expf(-sm));
    float tval = th[0];
    float val = r[d] * (maskv > tval ? 1.f : 0.f) + noise;
    float m = val;
    #pragma unroll
    for (int off = 32; off > 0; off >>= 1) m = fmaxf(m, __shfl_xor(m, off, 64));
    float e = __expf(val - m);
    float ssum = e;
    #pragma unroll
    for (int off = 32; off > 0; off >>= 1) ssum += __shfl_xor(ssum, off, 64);
    const float res = e / ssum;
    const int hh = rowi >> 8;
    const int a  = rowi & 255;
    unsigned short hb = f2bf(res);
    const size_t tix = ((size_t)hh * DHEAD + d) * ANUM + a;
    kth[tix] = hb;
    ktm[tix] = f2bf(res - bf2f(hb));
}

// ---------------- K5: out = softmax_a(q.agent*s) @ kvf via MFMA ----------------
__global__ __launch_bounds__(256, 3) void k_out_mfma(
        const unsigned short* __restrict__ qb,
        const unsigned short* __restrict__ agh, const unsigned short* __restrict__ agm,
        const unsigned short* __restrict__ kth, const unsigned short* __restrict__ ktm,
        float* __restrict__ out) {
    __shared__ __align__(16) unsigned short qt[64 * 64];    // [tok][d] swizzled
    __shared__ __align__(16) unsigned short P[64 * 256];    // [tok][agent] swizzled
    __shared__ float s_red[4][64];
    const int t = threadIdx.x;
    const int lane = t & 63;
    const int w = t >> 6;
    const int h = blockIdx.y;
    const int n0 = blockIdx.x * 64;
    {
        const int row = t >> 2;
        const unsigned short* src = qb + (size_t)(n0 + row) * DIMX + h * DHEAD + (t & 3) * 16;
        uint4 v0 = *(const uint4*)src;
        uint4 v1 = *(const uint4*)(src + 8);
        const int b = row * 128 + (t & 3) * 32;
        const int sw = (row & 7) << 4;
        *(uint4*)((char*)qt + ((b) ^ sw)) = v0;
        *(uint4*)((char*)qt + ((b + 16) ^ sw)) = v1;
    }
    __syncthreads();
    const int fr = lane & 15;
    const int fc = lane >> 4;
    v4f C[4][4];
    #pragma unroll
    for (int i = 0; i < 4; ++i)
        #pragma unroll
        for (int j = 0; j < 4; ++j)
            #pragma unroll
            for (int r = 0; r < 4; ++r) C[i][j][r] = 0.f;
    v8bf qa[4][2];
    #pragma unroll
    for (int mt = 0; mt < 4; ++mt) {
        const int tok = mt * 16 + fr;
        const int sw = (tok & 7) << 4;
        #pragma unroll
        for (int ks = 0; ks < 2; ++ks)
            qa[mt][ks] = *(const v8bf*)((const char*)qt + ((tok * 128 + fc * 16 + ks * 64) ^ sw));
    }
    const int a0w = w * 64;
    #pragma unroll
    for (int nt = 0; nt < 4; ++nt) {
        const size_t bix = ((size_t)h * ANUM + a0w + nt * 16 + fr) * DHEAD + fc * 8;
        v8bf B0h = *(const v8bf*)(agh + bix);
        v8bf B1h = *(const v8bf*)(agh + bix + 32);
        v8bf B0m = *(const v8bf*)(agm + bix);
        v8bf B1m = *(const v8bf*)(agm + bix + 32);
        #pragma unroll
        for (int mt = 0; mt < 4; ++mt) {
            C[mt][nt] = __builtin_amdgcn_mfma_f32_16x16x32_bf16(qa[mt][0], B0h, C[mt][nt], 0, 0, 0);
            C[mt][nt] = __builtin_amdgcn_mfma_f32_16x16x32_bf16(qa[mt][1], B1h, C[mt][nt], 0, 0, 0);
            C[mt][nt] = __builtin_amdgcn_mfma_f32_16x16x32_bf16(qa[mt][0], B0m, C[mt][nt], 0, 0, 0);
            C[mt][nt] = __builtin_amdgcn_mfma_f32_16x16x32_bf16(qa[mt][1], B1m, C[mt][nt], 0, 0, 0);
        }
    }
    #pragma unroll
    for (int mt = 0; mt < 4; ++mt)
        #pragma unroll
        for (int r = 0; r < 4; ++r) {
            const int tok = mt * 16 + fc * 4 + r;
            const int sw = (tok & 7) << 4;
            float pv[4];
            float sloc = 0.f;
            #pragma unroll
            for (int nt = 0; nt < 4; ++nt) {
                pv[nt] = __expf(C[mt][nt][r] * SCALE_Q);
                sloc += pv[nt];
            }
            #pragma unroll
            for (int m = 1; m < 16; m <<= 1) sloc += __shfl_xor(sloc, m, 64);
            if (fr == 0) s_red[w][tok] = sloc;
            #pragma unroll
            for (int nt = 0; nt < 4; ++nt) {
                const int ag = a0w + nt * 16 + fr;
                *(unsigned short*)((char*)P + ((tok * 512 + ag * 2) ^ sw)) = f2bf(pv[nt]);
            }
        }
    __syncthreads();
    v4f D[4];
    #pragma unroll
    for (int i = 0; i < 4; ++i)
        #pragma unroll
        for (int r = 0; r < 4; ++r) D[i][r] = 0.f;
    const int tokA = w * 16 + fr;
    const int swA = (tokA & 7) << 4;
    #pragma unroll
    for (int ks = 0; ks < 8; ++ks) {
        v8bf pa = *(const v8bf*)((const char*)P + ((tokA * 512 + fc * 16 + ks * 64) ^ swA));
        #pragma unroll
        for (int nt = 0; nt < 4; ++nt) {
            const size_t bix = ((size_t)h * DHEAD + nt * 16 + fr) * ANUM + fc * 8 + ks * 32;
            v8bf vh = *(const v8bf*)(kth + bix);
            v8bf vm = *(const v8bf*)(ktm + bix);
            D[nt] = __builtin_amdgcn_mfma_f32_16x16x32_bf16(pa, vh, D[nt], 0, 0, 0);
            D[nt] = __builtin_amdgcn_mfma_f32_16x16x32_bf16(pa, vm, D[nt], 0, 0, 0);
        }
    }
    float inv[4];
    #pragma unroll
    for (int r = 0; r < 4; ++r) {
        const int tok = w * 16 + fc * 4 + r;
        inv[r] = 1.f / (s_red[0][tok] + s_red[1][tok] + s_red[2][tok] + s_red[3][tok]);
    }
    #pragma unroll
    for (int nt = 0; nt < 4; ++nt)
        #pragma unroll
        for (int r = 0; r < 4; ++r) {
            const int tok = w * 16 + fc * 4 + r;
            out[(size_t)(n0 + tok) * DIMX + h * DHEAD + nt * 16 + fr] = D[nt][r] * inv[r];
        }
}

extern "C" void kernel_launch(void* const* d_in, const int* in_sizes, int n_in,
                              void* d_out, int out_size, void* d_ws, size_t ws_size,
                              hipStream_t stream) {
    const float* x     = (const float*)d_in[0];
    const float* Wqkv  = (const float*)d_in[1];
    const float* agent = (const float*)d_in[2];
    const float* Wn    = (const float*)d_in[3];
    const float* bn    = (const float*)d_in[4];
    const float* Wm    = (const float*)d_in[5];
    const float* bm    = (const float*)d_in[6];
    const float* Wt    = (const float*)d_in[7];
    const float* bt    = (const float*)d_in[8];
    float* out = (float*)d_out;

    const size_t KB_F  = (size_t)N_TOK * 512;         // k fp32
    const size_t VB_E  = (size_t)N_TOK * 512;         // v bf16 per split
    const size_t QB_E  = (size_t)N_TOK * DIMX;
    const size_t WSP_E = (size_t)3 * DIMX * DIMX;
    const size_t XSP_E = (size_t)STRIP * DIMX;
    const size_t PACC_F = (size_t)NCHUNK * HEADS * ANUM * DHEAD;
    const size_t PSUM_F = (size_t)NCHUNK * HEADS * ANUM;
    const size_t KV_F   = (size_t)HEADS * ANUM * DHEAD;   // 131072

    char* p = (char*)d_ws;
    float* kvb = (float*)p;            p += KB_F * 4;
    unsigned short* vhg = (unsigned short*)p;  p += VB_E * 2;
    unsigned short* vmg = (unsigned short*)p;  p += VB_E * 2;
    unsigned short* qbuf = (unsigned short*)p; p += QB_E * 2;
    unsigned short* wh = (unsigned short*)p;   p += WSP_E * 2;
    unsigned short* wm = (unsigned short*)p;   p += WSP_E * 2;
    unsigned short* wl = (unsigned short*)p;   p += WSP_E * 2;
    unsigned short* xh = (unsigned short*)p;   p += XSP_E * 2;
    unsigned short* xm = (unsigned short*)p;   p += XSP_E * 2;
    unsigned short* xl = (unsigned short*)p;   p += XSP_E * 2;
    float* pacc = (float*)p;           p += PACC_F * 4;
    float* psum = (float*)p;           p += PSUM_F * 4;
    float* kv   = (float*)p;           p += KV_F * 4;
    unsigned short* agh = (unsigned short*)p;  p += KV_F * 2;
    unsigned short* agm = (unsigned short*)p;  p += KV_F * 2;
    unsigned short* agl = (unsigned short*)p;  p += KV_F * 2;
    unsigned short* kth = (unsigned short*)p;  p += KV_F * 2;
    unsigned short* ktm = (unsigned short*)p;  p += KV_F * 2;
    float* th   = (float*)p;           p += 64;
    if (ws_size < (size_t)(p - (char*)d_ws)) return;

    k_cvt3<<<768, 256, 0, stream>>>(Wqkv, wh, wm, wl, (int)(WSP_E / 4));
    k_cvt3<<<128, 256, 0, stream>>>(agent, agh, agm, agl, (int)(KV_F / 4));
    for (int s = 0; s < N_TOK / STRIP; ++s) {
        k_cvt3<<<2048, 256, 0, stream>>>(x + (size_t)s * STRIP * DIMX, xh, xm, xl,
                                         (int)(XSP_E / 4));
        k_gemm<<<dim3(12, STRIP / 128), 256, 0, stream>>>(xh, xm, xl, wh, wm, wl,
                                                          qbuf, kvb, vhg, vmg, s * STRIP);
    }
    k_kvagg <<<dim3(HEADS, NCHUNK), 512, 0, stream>>>(kvb, vhg, vmg, agh, agm, agl,
                                                      pacc, psum);
    k_combine<<<512, 256, 0, stream>>>(pacc, psum, kv);
    k_thresh<<<1, 256, 0, stream>>>(kv, Wt, bt, th);
    k_gate  <<<HEADS*ANUM, 64, 0, stream>>>(kv, Wn, bn, Wm, bm, th, kth, ktm);
    k_out_mfma<<<dim3(N_TOK/64, HEADS), 256, 0, stream>>>(qbuf, agh, agm, kth, ktm, out);
}